// Round 4
// baseline (717.234 us; speedup 1.0000x reference)
//
#include <hip/hip_runtime.h>
#include <math.h>

#define NSN 4760
#define KNN 16
#define NT 6
#define NB 16

#ifndef __has_builtin
#define __has_builtin(x) 0
#endif

typedef _Float16 h2 __attribute__((ext_vector_type(2)));
typedef _Float16 h4 __attribute__((ext_vector_type(4)));
typedef _Float16 h8 __attribute__((ext_vector_type(8)));

__device__ __forceinline__ float fdot2f(h2 a, h2 b, float c) {
#if __has_builtin(__builtin_amdgcn_fdot2)
  return __builtin_amdgcn_fdot2(a, b, c, false);
#else
  return c + (float)a.x * (float)b.x + (float)a.y * (float)b.y;
#endif
}

__device__ __forceinline__ float rl_f(float v, int lane) {
  return __builtin_bit_cast(float, __builtin_amdgcn_readlane(__builtin_bit_cast(int, v), lane));
}
__device__ __forceinline__ h2 rl_h2(int v, int lane) {
  return __builtin_bit_cast(h2, __builtin_amdgcn_readlane(v, lane));
}

// ---------------- Kernel A: per-sensor precompute (batch independent) ------
// Each wave handles 4 sensors; weight columns loaded once serve 4 sensors.
__global__ void precompute_sensor(const float* __restrict__ pos_emb,
    const float* __restrict__ face_emb, const int* __restrict__ face_ids,
    const float* __restrict__ W_nbr, const float* __restrict__ b_nbr,
    const float* __restrict__ W_ql, const float* __restrict__ b_ql,
    const float* __restrict__ W_qg, const float* __restrict__ b_qg,
    float* __restrict__ S, float* __restrict__ qlocal,
    float* __restrict__ qg, float* __restrict__ c01)
{
  __shared__ __align__(16) float qT[4][128][4];   // [wave][dim][sensor]
  const int w = threadIdx.x >> 6, lane = threadIdx.x & 63;
  const int grp = blockIdx.x * 4 + w;
  if (grp >= NSN / 4) return;
  const int n0 = grp * 4;
  #pragma unroll
  for (int si = 0; si < 4; ++si) {
    const int n = n0 + si;
    const int fid = face_ids[n];
    const int e1 = lane + 64;
    qT[w][lane][si] = pos_emb[n * 96 + lane];
    qT[w][e1][si] = (e1 < 96) ? pos_emb[n * 96 + e1] : face_emb[fid * 32 + (e1 - 96)];
  }
  const float bn = b_nbr[lane], bq = b_ql[lane];
  const float bg0 = b_qg[lane], bg1 = b_qg[lane + 64];
  float s[4], ql[4], g0[4], g1[4];
  #pragma unroll
  for (int si = 0; si < 4; ++si) { s[si] = bn; ql[si] = bq; g0[si] = bg0; g1[si] = bg1; }
  #pragma unroll 2
  for (int i = 0; i < 128; ++i) {
    const float wn  = W_nbr[(2 + i) * 64 + lane];
    const float wq  = W_ql[i * 64 + lane];
    const float wg0 = W_qg[i * 128 + lane];
    const float wg1 = W_qg[i * 128 + 64 + lane];
    const float4 qv = *(const float4*)&qT[w][i][0];
    s[0]  += qv.x * wn;  s[1]  += qv.y * wn;  s[2]  += qv.z * wn;  s[3]  += qv.w * wn;
    ql[0] += qv.x * wq;  ql[1] += qv.y * wq;  ql[2] += qv.z * wq;  ql[3] += qv.w * wq;
    g0[0] += qv.x * wg0; g0[1] += qv.y * wg0; g0[2] += qv.z * wg0; g0[3] += qv.w * wg0;
    g1[0] += qv.x * wg1; g1[1] += qv.y * wg1; g1[2] += qv.z * wg1; g1[3] += qv.w * wg1;
  }
  const float wn0 = W_nbr[lane], wn1 = W_nbr[64 + lane];
  #pragma unroll
  for (int si = 0; si < 4; ++si) {
    const int n = n0 + si;
    S[n * 64 + lane] = s[si];
    qlocal[n * 64 + lane] = ql[si];
    qg[n * 128 + lane] = g0[si];
    qg[n * 128 + 64 + lane] = g1[si];
    float p0 = wn0 * ql[si], p1 = wn1 * ql[si];
    #pragma unroll
    for (int o = 32; o; o >>= 1) { p0 += __shfl_xor(p0, o); p1 += __shfl_xor(p1, o); }
    if (lane == 0) { c01[2 * n] = p0; c01[2 * n + 1] = p1; }
  }
}

// ---------------- Kernel B: latent -> K/V (96 rows) ------------------------
__global__ void precompute_latent(const float* __restrict__ latent,
    const float* __restrict__ face_emb,
    const float* __restrict__ W_lat, const float* __restrict__ b_lat,
    const float* __restrict__ W_lf, const float* __restrict__ b_lf,
    const float* __restrict__ W_k, const float* __restrict__ b_k,
    const float* __restrict__ W_v, const float* __restrict__ b_v,
    float* __restrict__ kg, float* __restrict__ vg)
{
  __shared__ __align__(16) float lat[1024];
  __shared__ __align__(16) float kv[128];
  const int bt = blockIdx.x;
  const int t = bt % NT;
  const int o = threadIdx.x;
  for (int i = o; i < 1024; i += 128) lat[i] = latent[bt * 1024 + i];
  __syncthreads();
  float acc = b_lat[o] + b_lf[o];
  #pragma unroll 8
  for (int i = 0; i < 1024; ++i) acc += lat[i] * W_lat[i * 128 + o];
  #pragma unroll
  for (int i = 0; i < 32; ++i) acc += face_emb[t * 32 + i] * W_lf[i * 128 + o];
  kv[o] = acc;
  __syncthreads();
  float kk = b_k[o], vv = b_v[o];
  #pragma unroll 4
  for (int i = 0; i < 128; ++i) {
    const float c = kv[i];
    kk += c * W_k[i * 128 + o];
    vv += c * W_v[i * 128 + o];
  }
  kg[bt * 128 + o] = kk;
  vg[bt * 128 + o] = vv;
}

// ---------------- Main fused kernel: one wave per (b,n), 8 waves/block -----
__launch_bounds__(512, 4)
__global__ void fused_main(const float* __restrict__ x_flat,
    const int* __restrict__ mask, const int* __restrict__ knn,
    const float* __restrict__ Wnbr,
    const float* __restrict__ S, const float* __restrict__ qlocal,
    const float* __restrict__ qg, const float* __restrict__ c01,
    const float* __restrict__ kg, const float* __restrict__ vg,
    const float* __restrict__ Wgo, const float* __restrict__ bgo,
    const float* __restrict__ lng, const float* __restrict__ lnb,
    const float* __restrict__ Wm1, const float* __restrict__ bm1,
    const float* __restrict__ Wm2, const float* __restrict__ bm2,
    float* __restrict__ out)
{
  // WgS4[i2*64+o2] = (Wgo[2i2][2o2], Wgo[2i2+1][2o2], Wgo[2i2][2o2+1], Wgo[2i2+1][2o2+1])
  __shared__ __align__(16) h4 WgS4[64 * 64];        // 32768 B
  // WmT[o*100 + i2] = (Wm1[2i2][o], Wm1[2i2+1][o]) ; stride 100 h2 for bank spread
  __shared__ __align__(16) h2 WmT[64 * 100];        // 25600 B
  __shared__ __align__(16) float qlS[8][64];        // 2048 B -> total 60416 B

  const int tid = threadIdx.x;
  for (int idx = tid; idx < 64 * 64; idx += 512) {
    const int i2 = idx >> 6, o2 = idx & 63;
    const float2 r0 = *(const float2*)(Wgo + (2 * i2) * 128 + 2 * o2);
    const float2 r1 = *(const float2*)(Wgo + (2 * i2 + 1) * 128 + 2 * o2);
    h4 v; v[0] = (_Float16)r0.x; v[1] = (_Float16)r1.x; v[2] = (_Float16)r0.y; v[3] = (_Float16)r1.y;
    WgS4[i2 * 64 + o2] = v;
  }
  for (int idx = tid; idx < 96 * 64; idx += 512) {
    const int i2 = idx >> 6, o = idx & 63;
    h2 v; v[0] = (_Float16)Wm1[(2 * i2) * 64 + o]; v[1] = (_Float16)Wm1[(2 * i2 + 1) * 64 + o];
    WmT[o * 100 + i2] = v;
  }
  __syncthreads();

  const int w = tid >> 6, lane = tid & 63;
  // hoisted per-lane constants
  const float w0 = Wnbr[lane], w1 = Wnbr[64 + lane];
  const float bgo0 = bgo[2 * lane], bgo1 = bgo[2 * lane + 1];
  const float lng_a  = lng[lane],           lnb_a  = lnb[lane];
  const float lng_b0 = lng[64 + 2 * lane],  lnb_b0 = lnb[64 + 2 * lane];
  const float lng_b1 = lng[65 + 2 * lane],  lnb_b1 = lnb[65 + 2 * lane];
  const float bm1_l = bm1[lane], wm2_l = Wm2[lane], bm2_s = bm2[0];

  const int stride = gridDim.x * 8;
  for (int item = blockIdx.x * 8 + w; item < NB * NSN; item += stride) {
    const int b = item / NSN;
    const int n = item - b * NSN;

    // ---- stage per-item vectors ----
    const float ql = qlocal[n * 64 + lane];
    qlS[w][lane] = ql;
    int jv = 0; float x0 = 0.f, x1 = 0.f;
    if (lane < 16) {
      jv = knn[n * 16 + lane];
      const float2 x01 = *(const float2*)(x_flat + (size_t)(b * NSN + jv) * 2);
      x0 = x01.x; x1 = x01.y;
    }

    // ---- Pass 1: KNN logits (4 lanes per neighbor k) ----
    const int k = lane >> 2, d = lane & 3;
    const int jk = __shfl(jv, k);
    const float4* Sr = (const float4*)(S + jk * 64 + d * 16);
    const float4* qr = (const float4*)(&qlS[w][d * 16]);
    float acc = 0.f;
    #pragma unroll
    for (int i = 0; i < 4; ++i) {
      const float4 sv = Sr[i]; const float4 qv = qr[i];
      acc += sv.x * qv.x + sv.y * qv.y + sv.z * qv.z + sv.w * qv.w;
    }
    acc += __shfl_xor(acc, 1); acc += __shfl_xor(acc, 2);
    const float c0 = c01[2 * n], c1 = c01[2 * n + 1];
    const float xk0 = __shfl(x0, k), xk1 = __shfl(x1, k);
    float logit = (acc + xk0 * c0 + xk1 * c1) * 0.125f;
    if (mask[b * NSN + jk] != 0) logit = -10000.0f;
    float mx = logit;
    mx = fmaxf(mx, __shfl_xor(mx, 4));  mx = fmaxf(mx, __shfl_xor(mx, 8));
    mx = fmaxf(mx, __shfl_xor(mx, 16)); mx = fmaxf(mx, __shfl_xor(mx, 32));
    const float e = __expf(logit - mx);
    float s4 = e;
    s4 += __shfl_xor(s4, 4); s4 += __shfl_xor(s4, 8);
    s4 += __shfl_xor(s4, 16); s4 += __shfl_xor(s4, 32);   // = sum over the 16 k
    const float attn = e / s4;
    float ax0 = attn * xk0, ax1 = attn * xk1;
    ax0 += __shfl_xor(ax0, 4); ax0 += __shfl_xor(ax0, 8);
    ax0 += __shfl_xor(ax0, 16); ax0 += __shfl_xor(ax0, 32);
    ax1 += __shfl_xor(ax1, 4); ax1 += __shfl_xor(ax1, 8);
    ax1 += __shfl_xor(ax1, 16); ax1 += __shfl_xor(ax1, 32);

    // ---- Pass 2: local_feat[h] (lane = h), attn/j broadcast via readlane ----
    float lf = ax0 * w0 + ax1 * w1;
    #pragma unroll
    for (int kk = 0; kk < 16; ++kk) {
      const int jr = __builtin_amdgcn_readlane(jv, kk);
      const float aw = rl_f(attn, 4 * kk);
      lf += aw * S[jr * 64 + lane];
    }

    // ---- Phase B: global attention (head h = lane>>4, dims 2l,2l+1) ----
    const float2 q2 = *(const float2*)(qg + n * 128 + 2 * lane);
    const float2* kgb = (const float2*)(kg + b * NT * 128);
    const float2* vgb = (const float2*)(vg + b * NT * 128);
    float gl[NT];
    #pragma unroll
    for (int t = 0; t < NT; ++t) {
      const float2 k2 = kgb[t * 64 + lane];
      float p = q2.x * k2.x + q2.y * k2.y;
      p += __shfl_xor(p, 1); p += __shfl_xor(p, 2);
      p += __shfl_xor(p, 4); p += __shfl_xor(p, 8);
      gl[t] = p * 0.17677669529663687f;   // 1/sqrt(32)
    }
    float gm = gl[0];
    #pragma unroll
    for (int t = 1; t < NT; ++t) gm = fmaxf(gm, gl[t]);
    float gs = 0.f;
    #pragma unroll
    for (int t = 0; t < NT; ++t) { gl[t] = __expf(gl[t] - gm); gs += gl[t]; }
    const float ginv = 1.0f / gs;
    float gfx = 0.f, gfy = 0.f;
    #pragma unroll
    for (int t = 0; t < NT; ++t) {
      const float2 v2 = vgb[t * 64 + lane];
      const float a = gl[t] * ginv;
      gfx += a * v2.x; gfy += a * v2.y;
    }
    h2 gp; gp[0] = (_Float16)gfx; gp[1] = (_Float16)gfy;
    const int gpi = __builtin_bit_cast(int, gp);

    // ---- Phase C: g_out = g_feat @ W_go (+b); lane -> outputs 2l, 2l+1 ----
    float a0 = 0.f, a1 = 0.f;
    #pragma unroll
    for (int i2 = 0; i2 < 64; ++i2) {
      const h2 g2 = rl_h2(gpi, i2);
      const h4 wv = WgS4[i2 * 64 + lane];
      const h2 wlo = __builtin_shufflevector(wv, wv, 0, 1);
      const h2 whi = __builtin_shufflevector(wv, wv, 2, 3);
      a0 = fdot2f(g2, wlo, a0);
      a1 = fdot2f(g2, whi, a1);
    }
    const float go0 = a0 + bgo0, go1 = a1 + bgo1;

    // ---- Phase D: LayerNorm over 192 (c[l], c[64+2l], c[65+2l]) ----
    float s1 = lf + go0 + go1;
    float s2 = lf * lf + go0 * go0 + go1 * go1;
    #pragma unroll
    for (int o = 32; o; o >>= 1) { s1 += __shfl_xor(s1, o); s2 += __shfl_xor(s2, o); }
    const float mu  = s1 * (1.0f / 192.0f);
    const float var = s2 * (1.0f / 192.0f) - mu * mu;
    const float rinv = rsqrtf(var + 1e-5f);
    const float n0v = (lf  - mu) * rinv * lng_a  + lnb_a;
    const float n1v = (go0 - mu) * rinv * lng_b0 + lnb_b0;
    const float n2v = (go1 - mu) * rinv * lng_b1 + lnb_b1;
    // pack normed for readlane broadcast: pair m (dims 2m,2m+1) on lane m (m<32);
    // pair 32+l (dims 64+2l,65+2l) on lane l
    const float pl = __shfl(n0v, lane * 2);
    const float ph = __shfl(n0v, lane * 2 + 1);
    h2 lo2; lo2[0] = (_Float16)pl;  lo2[1] = (_Float16)ph;
    h2 hi2; hi2[0] = (_Float16)n1v; hi2[1] = (_Float16)n2v;
    const int clo = __builtin_bit_cast(int, lo2);
    const int chi = __builtin_bit_cast(int, hi2);

    // ---- Phase E: MLP: normed @ W_m1 (+b), GELU(exact), @ W_m2 (+b) ----
    float m1a = bm1_l;
    #pragma unroll
    for (int g = 0; g < 24; ++g) {
      const h8 ww = *(const h8*)&WmT[lane * 100 + g * 4];
      const int i2b = g * 4;
      {
        const int i2 = i2b + 0;
        const h2 cc = (i2 < 32) ? rl_h2(clo, i2) : rl_h2(chi, i2 - 32);
        const h2 wp = __builtin_shufflevector(ww, ww, 0, 1);
        m1a = fdot2f(cc, wp, m1a);
      }
      {
        const int i2 = i2b + 1;
        const h2 cc = (i2 < 32) ? rl_h2(clo, i2) : rl_h2(chi, i2 - 32);
        const h2 wp = __builtin_shufflevector(ww, ww, 2, 3);
        m1a = fdot2f(cc, wp, m1a);
      }
      {
        const int i2 = i2b + 2;
        const h2 cc = (i2 < 32) ? rl_h2(clo, i2) : rl_h2(chi, i2 - 32);
        const h2 wp = __builtin_shufflevector(ww, ww, 4, 5);
        m1a = fdot2f(cc, wp, m1a);
      }
      {
        const int i2 = i2b + 3;
        const h2 cc = (i2 < 32) ? rl_h2(clo, i2) : rl_h2(chi, i2 - 32);
        const h2 wp = __builtin_shufflevector(ww, ww, 6, 7);
        m1a = fdot2f(cc, wp, m1a);
      }
    }
    const float gelu = 0.5f * m1a * (1.0f + erff(m1a * 0.7071067811865476f));
    float pr = gelu * wm2_l;
    #pragma unroll
    for (int o = 32; o; o >>= 1) pr += __shfl_xor(pr, o);
    float res = pr + bm2_s;
    if (mask[item] == 0) res = 0.f;   // preds * (mask != 0)
    if (lane == 0) out[item] = res;
  }
}

extern "C" void kernel_launch(void* const* d_in, const int* in_sizes, int n_in,
                              void* d_out, int out_size, void* d_ws, size_t ws_size,
                              hipStream_t stream) {
  (void)in_sizes; (void)n_in; (void)out_size; (void)ws_size;
  const float* x_flat   = (const float*)d_in[0];
  const float* latent   = (const float*)d_in[1];
  const float* pos_emb  = (const float*)d_in[2];
  const float* face_emb = (const float*)d_in[3];
  const float* W_nbr = (const float*)d_in[4];
  const float* b_nbr = (const float*)d_in[5];
  const float* W_ql  = (const float*)d_in[6];
  const float* b_ql  = (const float*)d_in[7];
  const float* W_lat = (const float*)d_in[8];
  const float* b_lat = (const float*)d_in[9];
  const float* W_lf  = (const float*)d_in[10];
  const float* b_lf  = (const float*)d_in[11];
  const float* W_qg  = (const float*)d_in[12];
  const float* b_qg  = (const float*)d_in[13];
  const float* W_k   = (const float*)d_in[14];
  const float* b_k   = (const float*)d_in[15];
  const float* W_v   = (const float*)d_in[16];
  const float* b_v   = (const float*)d_in[17];
  const float* W_go  = (const float*)d_in[18];
  const float* b_go  = (const float*)d_in[19];
  const float* ln_g  = (const float*)d_in[20];
  const float* ln_b  = (const float*)d_in[21];
  const float* W_m1  = (const float*)d_in[22];
  const float* b_m1  = (const float*)d_in[23];
  const float* W_m2  = (const float*)d_in[24];
  const float* b_m2  = (const float*)d_in[25];
  const int* mask     = (const int*)d_in[26];
  const int* knn      = (const int*)d_in[27];
  const int* face_ids = (const int*)d_in[28];
  float* out = (float*)d_out;

  float* ws = (float*)d_ws;
  float* S      = ws;  ws += NSN * 64;
  float* qlocal = ws;  ws += NSN * 64;
  float* qgb    = ws;  ws += NSN * 128;
  float* c01    = ws;  ws += NSN * 2;
  float* kgb    = ws;  ws += NB * NT * 128;
  float* vgb    = ws;  ws += NB * NT * 128;

  precompute_sensor<<<298, 256, 0, stream>>>(pos_emb, face_emb, face_ids,
      W_nbr, b_nbr, W_ql, b_ql, W_qg, b_qg, S, qlocal, qgb, c01);
  precompute_latent<<<96, 128, 0, stream>>>(latent, face_emb, W_lat, b_lat,
      W_lf, b_lf, W_k, b_k, W_v, b_v, kgb, vgb);
  fused_main<<<512, 512, 0, stream>>>(x_flat, mask, knn, W_nbr,
      S, qlocal, qgb, c01, kgb, vgb, W_go, b_go, ln_g, ln_b,
      W_m1, b_m1, W_m2, b_m2, out);
}

// Round 5
// 492.626 us; speedup vs baseline: 1.4559x; 1.4559x over previous
//
#include <hip/hip_runtime.h>
#include <math.h>

#define NSN 4760
#define KNN 16
#define NT 6
#define NB 16

#ifndef __has_builtin
#define __has_builtin(x) 0
#endif

typedef _Float16 h2 __attribute__((ext_vector_type(2)));
typedef _Float16 h4 __attribute__((ext_vector_type(4)));
typedef _Float16 h8 __attribute__((ext_vector_type(8)));

__device__ __forceinline__ float fdot2f(h2 a, h2 b, float c) {
#if __has_builtin(__builtin_amdgcn_fdot2)
  return __builtin_amdgcn_fdot2(a, b, c, false);
#else
  return c + (float)a.x * (float)b.x + (float)a.y * (float)b.y;
#endif
}

__device__ __forceinline__ float rl_f(float v, int lane) {
  return __builtin_bit_cast(float, __builtin_amdgcn_readlane(__builtin_bit_cast(int, v), lane));
}
__device__ __forceinline__ h2 rl_h2(int v, int lane) {
  return __builtin_bit_cast(h2, __builtin_amdgcn_readlane(v, lane));
}

// ---------------- Kernel A: per-sensor precompute (batch independent) ------
// Each wave handles 4 sensors; weight columns loaded once serve 4 sensors.
__global__ void precompute_sensor(const float* __restrict__ pos_emb,
    const float* __restrict__ face_emb, const int* __restrict__ face_ids,
    const float* __restrict__ W_nbr, const float* __restrict__ b_nbr,
    const float* __restrict__ W_ql, const float* __restrict__ b_ql,
    const float* __restrict__ W_qg, const float* __restrict__ b_qg,
    float* __restrict__ S, float* __restrict__ qlocal,
    float* __restrict__ qg, float* __restrict__ c01)
{
  __shared__ __align__(16) float qT[4][128][4];   // [wave][dim][sensor]
  const int w = threadIdx.x >> 6, lane = threadIdx.x & 63;
  const int grp = blockIdx.x * 4 + w;
  if (grp >= NSN / 4) return;
  const int n0 = grp * 4;
  #pragma unroll
  for (int si = 0; si < 4; ++si) {
    const int n = n0 + si;
    const int fid = face_ids[n];
    const int e1 = lane + 64;
    qT[w][lane][si] = pos_emb[n * 96 + lane];
    qT[w][e1][si] = (e1 < 96) ? pos_emb[n * 96 + e1] : face_emb[fid * 32 + (e1 - 96)];
  }
  const float bn = b_nbr[lane], bq = b_ql[lane];
  const float bg0 = b_qg[lane], bg1 = b_qg[lane + 64];
  float s[4], ql[4], g0[4], g1[4];
  #pragma unroll
  for (int si = 0; si < 4; ++si) { s[si] = bn; ql[si] = bq; g0[si] = bg0; g1[si] = bg1; }
  #pragma unroll 2
  for (int i = 0; i < 128; ++i) {
    const float wn  = W_nbr[(2 + i) * 64 + lane];
    const float wq  = W_ql[i * 64 + lane];
    const float wg0 = W_qg[i * 128 + lane];
    const float wg1 = W_qg[i * 128 + 64 + lane];
    const float4 qv = *(const float4*)&qT[w][i][0];
    s[0]  += qv.x * wn;  s[1]  += qv.y * wn;  s[2]  += qv.z * wn;  s[3]  += qv.w * wn;
    ql[0] += qv.x * wq;  ql[1] += qv.y * wq;  ql[2] += qv.z * wq;  ql[3] += qv.w * wq;
    g0[0] += qv.x * wg0; g0[1] += qv.y * wg0; g0[2] += qv.z * wg0; g0[3] += qv.w * wg0;
    g1[0] += qv.x * wg1; g1[1] += qv.y * wg1; g1[2] += qv.z * wg1; g1[3] += qv.w * wg1;
  }
  const float wn0 = W_nbr[lane], wn1 = W_nbr[64 + lane];
  #pragma unroll
  for (int si = 0; si < 4; ++si) {
    const int n = n0 + si;
    S[n * 64 + lane] = s[si];
    qlocal[n * 64 + lane] = ql[si];
    qg[n * 128 + lane] = g0[si];
    qg[n * 128 + 64 + lane] = g1[si];
    float p0 = wn0 * ql[si], p1 = wn1 * ql[si];
    #pragma unroll
    for (int o = 32; o; o >>= 1) { p0 += __shfl_xor(p0, o); p1 += __shfl_xor(p1, o); }
    if (lane == 0) { c01[2 * n] = p0; c01[2 * n + 1] = p1; }
  }
}

// ---------------- Kernel B: latent -> K/V (96 rows) ------------------------
__global__ void precompute_latent(const float* __restrict__ latent,
    const float* __restrict__ face_emb,
    const float* __restrict__ W_lat, const float* __restrict__ b_lat,
    const float* __restrict__ W_lf, const float* __restrict__ b_lf,
    const float* __restrict__ W_k, const float* __restrict__ b_k,
    const float* __restrict__ W_v, const float* __restrict__ b_v,
    float* __restrict__ kg, float* __restrict__ vg)
{
  __shared__ __align__(16) float lat[1024];
  __shared__ __align__(16) float kv[128];
  const int bt = blockIdx.x;
  const int t = bt % NT;
  const int o = threadIdx.x;
  for (int i = o; i < 1024; i += 128) lat[i] = latent[bt * 1024 + i];
  __syncthreads();
  float acc = b_lat[o] + b_lf[o];
  #pragma unroll 8
  for (int i = 0; i < 1024; ++i) acc += lat[i] * W_lat[i * 128 + o];
  #pragma unroll
  for (int i = 0; i < 32; ++i) acc += face_emb[t * 32 + i] * W_lf[i * 128 + o];
  kv[o] = acc;
  __syncthreads();
  float kk = b_k[o], vv = b_v[o];
  #pragma unroll 4
  for (int i = 0; i < 128; ++i) {
    const float c = kv[i];
    kk += c * W_k[i * 128 + o];
    vv += c * W_v[i * 128 + o];
  }
  kg[bt * 128 + o] = kk;
  vg[bt * 128 + o] = vv;
}

// ---------------- Main fused kernel: one wave per (b,n), 8 waves/block -----
// NOTE: second __launch_bounds__ arg behaves as blocks/CU on this toolchain
// ((512,4) forced a 64-VGPR cap -> massive scratch spills, round 4).
// (512,2): cap 128 VGPR, 2 blocks/CU = 16 waves/CU, LDS 2x60.4KB fits 160KB.
__launch_bounds__(512, 2)
__global__ void fused_main(const float* __restrict__ x_flat,
    const int* __restrict__ mask, const int* __restrict__ knn,
    const float* __restrict__ Wnbr,
    const float* __restrict__ S, const float* __restrict__ qlocal,
    const float* __restrict__ qg, const float* __restrict__ c01,
    const float* __restrict__ kg, const float* __restrict__ vg,
    const float* __restrict__ Wgo, const float* __restrict__ bgo,
    const float* __restrict__ lng, const float* __restrict__ lnb,
    const float* __restrict__ Wm1, const float* __restrict__ bm1,
    const float* __restrict__ Wm2, const float* __restrict__ bm2,
    float* __restrict__ out)
{
  // WgS4[i2*64+o2] = (Wgo[2i2][2o2], Wgo[2i2+1][2o2], Wgo[2i2][2o2+1], Wgo[2i2+1][2o2+1])
  __shared__ __align__(16) h4 WgS4[64 * 64];        // 32768 B
  // WmT[o*100 + i2] = (Wm1[2i2][o], Wm1[2i2+1][o]) ; stride 100 h2 for bank spread
  __shared__ __align__(16) h2 WmT[64 * 100];        // 25600 B
  __shared__ __align__(16) float qlS[8][64];        // 2048 B -> total 60416 B

  const int tid = threadIdx.x;
  for (int idx = tid; idx < 64 * 64; idx += 512) {
    const int i2 = idx >> 6, o2 = idx & 63;
    const float2 r0 = *(const float2*)(Wgo + (2 * i2) * 128 + 2 * o2);
    const float2 r1 = *(const float2*)(Wgo + (2 * i2 + 1) * 128 + 2 * o2);
    h4 v; v[0] = (_Float16)r0.x; v[1] = (_Float16)r1.x; v[2] = (_Float16)r0.y; v[3] = (_Float16)r1.y;
    WgS4[i2 * 64 + o2] = v;
  }
  for (int idx = tid; idx < 96 * 64; idx += 512) {
    const int i2 = idx >> 6, o = idx & 63;
    h2 v; v[0] = (_Float16)Wm1[(2 * i2) * 64 + o]; v[1] = (_Float16)Wm1[(2 * i2 + 1) * 64 + o];
    WmT[o * 100 + i2] = v;
  }
  __syncthreads();

  const int w = tid >> 6, lane = tid & 63;
  // hoisted per-lane constants
  const float w0 = Wnbr[lane], w1 = Wnbr[64 + lane];
  const float bgo0 = bgo[2 * lane], bgo1 = bgo[2 * lane + 1];
  const float lng_a  = lng[lane],           lnb_a  = lnb[lane];
  const float lng_b0 = lng[64 + 2 * lane],  lnb_b0 = lnb[64 + 2 * lane];
  const float lng_b1 = lng[65 + 2 * lane],  lnb_b1 = lnb[65 + 2 * lane];
  const float bm1_l = bm1[lane], wm2_l = Wm2[lane], bm2_s = bm2[0];

  const int stride = gridDim.x * 8;
  for (int item = blockIdx.x * 8 + w; item < NB * NSN; item += stride) {
    const int b = item / NSN;
    const int n = item - b * NSN;

    // ---- stage per-item vectors ----
    const float ql = qlocal[n * 64 + lane];
    qlS[w][lane] = ql;
    int jv = 0; float x0 = 0.f, x1 = 0.f;
    if (lane < 16) {
      jv = knn[n * 16 + lane];
      const float2 x01 = *(const float2*)(x_flat + (size_t)(b * NSN + jv) * 2);
      x0 = x01.x; x1 = x01.y;
    }

    // ---- Pass 1: KNN logits (4 lanes per neighbor k) ----
    const int k = lane >> 2, d = lane & 3;
    const int jk = __shfl(jv, k);
    const float4* Sr = (const float4*)(S + jk * 64 + d * 16);
    const float4* qr = (const float4*)(&qlS[w][d * 16]);
    float acc = 0.f;
    #pragma unroll
    for (int i = 0; i < 4; ++i) {
      const float4 sv = Sr[i]; const float4 qv = qr[i];
      acc += sv.x * qv.x + sv.y * qv.y + sv.z * qv.z + sv.w * qv.w;
    }
    acc += __shfl_xor(acc, 1); acc += __shfl_xor(acc, 2);
    const float c0 = c01[2 * n], c1 = c01[2 * n + 1];
    const float xk0 = __shfl(x0, k), xk1 = __shfl(x1, k);
    float logit = (acc + xk0 * c0 + xk1 * c1) * 0.125f;
    if (mask[b * NSN + jk] != 0) logit = -10000.0f;
    float mx = logit;
    mx = fmaxf(mx, __shfl_xor(mx, 4));  mx = fmaxf(mx, __shfl_xor(mx, 8));
    mx = fmaxf(mx, __shfl_xor(mx, 16)); mx = fmaxf(mx, __shfl_xor(mx, 32));
    const float e = __expf(logit - mx);
    float s4 = e;
    s4 += __shfl_xor(s4, 4); s4 += __shfl_xor(s4, 8);
    s4 += __shfl_xor(s4, 16); s4 += __shfl_xor(s4, 32);   // = sum over the 16 k
    const float attn = e / s4;
    float ax0 = attn * xk0, ax1 = attn * xk1;
    ax0 += __shfl_xor(ax0, 4); ax0 += __shfl_xor(ax0, 8);
    ax0 += __shfl_xor(ax0, 16); ax0 += __shfl_xor(ax0, 32);
    ax1 += __shfl_xor(ax1, 4); ax1 += __shfl_xor(ax1, 8);
    ax1 += __shfl_xor(ax1, 16); ax1 += __shfl_xor(ax1, 32);

    // ---- Pass 2: local_feat[h] (lane = h), attn/j broadcast via readlane ----
    float lf = ax0 * w0 + ax1 * w1;
    #pragma unroll
    for (int kk = 0; kk < 16; ++kk) {
      const int jr = __builtin_amdgcn_readlane(jv, kk);
      const float aw = rl_f(attn, 4 * kk);
      lf += aw * S[jr * 64 + lane];
    }

    // ---- Phase B: global attention (head h = lane>>4, dims 2l,2l+1) ----
    const float2 q2 = *(const float2*)(qg + n * 128 + 2 * lane);
    const float2* kgb = (const float2*)(kg + b * NT * 128);
    const float2* vgb = (const float2*)(vg + b * NT * 128);
    float gl[NT];
    #pragma unroll
    for (int t = 0; t < NT; ++t) {
      const float2 k2 = kgb[t * 64 + lane];
      float p = q2.x * k2.x + q2.y * k2.y;
      p += __shfl_xor(p, 1); p += __shfl_xor(p, 2);
      p += __shfl_xor(p, 4); p += __shfl_xor(p, 8);
      gl[t] = p * 0.17677669529663687f;   // 1/sqrt(32)
    }
    float gm = gl[0];
    #pragma unroll
    for (int t = 1; t < NT; ++t) gm = fmaxf(gm, gl[t]);
    float gs = 0.f;
    #pragma unroll
    for (int t = 0; t < NT; ++t) { gl[t] = __expf(gl[t] - gm); gs += gl[t]; }
    const float ginv = 1.0f / gs;
    float gfx = 0.f, gfy = 0.f;
    #pragma unroll
    for (int t = 0; t < NT; ++t) {
      const float2 v2 = vgb[t * 64 + lane];
      const float a = gl[t] * ginv;
      gfx += a * v2.x; gfy += a * v2.y;
    }
    h2 gp; gp[0] = (_Float16)gfx; gp[1] = (_Float16)gfy;
    const int gpi = __builtin_bit_cast(int, gp);

    // ---- Phase C: g_out = g_feat @ W_go (+b); lane -> outputs 2l, 2l+1 ----
    float a0 = 0.f, a1 = 0.f;
    #pragma unroll
    for (int i2 = 0; i2 < 64; ++i2) {
      const h2 g2 = rl_h2(gpi, i2);
      const h4 wv = WgS4[i2 * 64 + lane];
      const h2 wlo = __builtin_shufflevector(wv, wv, 0, 1);
      const h2 whi = __builtin_shufflevector(wv, wv, 2, 3);
      a0 = fdot2f(g2, wlo, a0);
      a1 = fdot2f(g2, whi, a1);
    }
    const float go0 = a0 + bgo0, go1 = a1 + bgo1;

    // ---- Phase D: LayerNorm over 192 (c[l], c[64+2l], c[65+2l]) ----
    float s1 = lf + go0 + go1;
    float s2 = lf * lf + go0 * go0 + go1 * go1;
    #pragma unroll
    for (int o = 32; o; o >>= 1) { s1 += __shfl_xor(s1, o); s2 += __shfl_xor(s2, o); }
    const float mu  = s1 * (1.0f / 192.0f);
    const float var = s2 * (1.0f / 192.0f) - mu * mu;
    const float rinv = rsqrtf(var + 1e-5f);
    const float n0v = (lf  - mu) * rinv * lng_a  + lnb_a;
    const float n1v = (go0 - mu) * rinv * lng_b0 + lnb_b0;
    const float n2v = (go1 - mu) * rinv * lng_b1 + lnb_b1;
    // pack normed for readlane broadcast: pair m (dims 2m,2m+1) on lane m (m<32);
    // pair 32+l (dims 64+2l,65+2l) on lane l
    const float pl = __shfl(n0v, lane * 2);
    const float ph = __shfl(n0v, lane * 2 + 1);
    h2 lo2; lo2[0] = (_Float16)pl;  lo2[1] = (_Float16)ph;
    h2 hi2; hi2[0] = (_Float16)n1v; hi2[1] = (_Float16)n2v;
    const int clo = __builtin_bit_cast(int, lo2);
    const int chi = __builtin_bit_cast(int, hi2);

    // ---- Phase E: MLP: normed @ W_m1 (+b), GELU(exact), @ W_m2 (+b) ----
    float m1a = bm1_l;
    #pragma unroll
    for (int g = 0; g < 24; ++g) {
      const h8 ww = *(const h8*)&WmT[lane * 100 + g * 4];
      const int i2b = g * 4;
      {
        const int i2 = i2b + 0;
        const h2 cc = (i2 < 32) ? rl_h2(clo, i2) : rl_h2(chi, i2 - 32);
        const h2 wp = __builtin_shufflevector(ww, ww, 0, 1);
        m1a = fdot2f(cc, wp, m1a);
      }
      {
        const int i2 = i2b + 1;
        const h2 cc = (i2 < 32) ? rl_h2(clo, i2) : rl_h2(chi, i2 - 32);
        const h2 wp = __builtin_shufflevector(ww, ww, 2, 3);
        m1a = fdot2f(cc, wp, m1a);
      }
      {
        const int i2 = i2b + 2;
        const h2 cc = (i2 < 32) ? rl_h2(clo, i2) : rl_h2(chi, i2 - 32);
        const h2 wp = __builtin_shufflevector(ww, ww, 4, 5);
        m1a = fdot2f(cc, wp, m1a);
      }
      {
        const int i2 = i2b + 3;
        const h2 cc = (i2 < 32) ? rl_h2(clo, i2) : rl_h2(chi, i2 - 32);
        const h2 wp = __builtin_shufflevector(ww, ww, 6, 7);
        m1a = fdot2f(cc, wp, m1a);
      }
    }
    const float gelu = 0.5f * m1a * (1.0f + erff(m1a * 0.7071067811865476f));
    float pr = gelu * wm2_l;
    #pragma unroll
    for (int o = 32; o; o >>= 1) pr += __shfl_xor(pr, o);
    float res = pr + bm2_s;
    if (mask[item] == 0) res = 0.f;   // preds * (mask != 0)
    if (lane == 0) out[item] = res;
  }
}

extern "C" void kernel_launch(void* const* d_in, const int* in_sizes, int n_in,
                              void* d_out, int out_size, void* d_ws, size_t ws_size,
                              hipStream_t stream) {
  (void)in_sizes; (void)n_in; (void)out_size; (void)ws_size;
  const float* x_flat   = (const float*)d_in[0];
  const float* latent   = (const float*)d_in[1];
  const float* pos_emb  = (const float*)d_in[2];
  const float* face_emb = (const float*)d_in[3];
  const float* W_nbr = (const float*)d_in[4];
  const float* b_nbr = (const float*)d_in[5];
  const float* W_ql  = (const float*)d_in[6];
  const float* b_ql  = (const float*)d_in[7];
  const float* W_lat = (const float*)d_in[8];
  const float* b_lat = (const float*)d_in[9];
  const float* W_lf  = (const float*)d_in[10];
  const float* b_lf  = (const float*)d_in[11];
  const float* W_qg  = (const float*)d_in[12];
  const float* b_qg  = (const float*)d_in[13];
  const float* W_k   = (const float*)d_in[14];
  const float* b_k   = (const float*)d_in[15];
  const float* W_v   = (const float*)d_in[16];
  const float* b_v   = (const float*)d_in[17];
  const float* W_go  = (const float*)d_in[18];
  const float* b_go  = (const float*)d_in[19];
  const float* ln_g  = (const float*)d_in[20];
  const float* ln_b  = (const float*)d_in[21];
  const float* W_m1  = (const float*)d_in[22];
  const float* b_m1  = (const float*)d_in[23];
  const float* W_m2  = (const float*)d_in[24];
  const float* b_m2  = (const float*)d_in[25];
  const int* mask     = (const int*)d_in[26];
  const int* knn      = (const int*)d_in[27];
  const int* face_ids = (const int*)d_in[28];
  float* out = (float*)d_out;

  float* ws = (float*)d_ws;
  float* S      = ws;  ws += NSN * 64;
  float* qlocal = ws;  ws += NSN * 64;
  float* qgb    = ws;  ws += NSN * 128;
  float* c01    = ws;  ws += NSN * 2;
  float* kgb    = ws;  ws += NB * NT * 128;
  float* vgb    = ws;  ws += NB * NT * 128;

  precompute_sensor<<<298, 256, 0, stream>>>(pos_emb, face_emb, face_ids,
      W_nbr, b_nbr, W_ql, b_ql, W_qg, b_qg, S, qlocal, qgb, c01);
  precompute_latent<<<96, 128, 0, stream>>>(latent, face_emb, W_lat, b_lat,
      W_lf, b_lf, W_k, b_k, W_v, b_v, kgb, vgb);
  fused_main<<<512, 512, 0, stream>>>(x_flat, mask, knn, W_nbr,
      S, qlocal, qgb, c01, kgb, vgb, W_go, b_go, ln_g, ln_b,
      W_m1, b_m1, W_m2, b_m2, out);
}

// Round 6
// 372.791 us; speedup vs baseline: 1.9240x; 1.3215x over previous
//
#include <hip/hip_runtime.h>
#include <math.h>

#define NSN 4760
#define KNN 16
#define NT 6
#define NB 16

#ifndef __has_builtin
#define __has_builtin(x) 0
#endif

typedef _Float16 h2 __attribute__((ext_vector_type(2)));
typedef _Float16 h4 __attribute__((ext_vector_type(4)));
typedef _Float16 h8 __attribute__((ext_vector_type(8)));

__device__ __forceinline__ float fdot2f(h2 a, h2 b, float c) {
#if __has_builtin(__builtin_amdgcn_fdot2)
  return __builtin_amdgcn_fdot2(a, b, c, false);
#else
  return c + (float)a.x * (float)b.x + (float)a.y * (float)b.y;
#endif
}

__device__ __forceinline__ float rl_f(float v, int lane) {
  return __builtin_bit_cast(float, __builtin_amdgcn_readlane(__builtin_bit_cast(int, v), lane));
}
__device__ __forceinline__ h2 rl_h2(int v, int lane) {
  return __builtin_bit_cast(h2, __builtin_amdgcn_readlane(v, lane));
}

// ---------------- Kernel A: per-sensor precompute (batch independent) ------
// Each wave handles 4 sensors; weight columns loaded once serve 4 sensors.
__global__ void precompute_sensor(const float* __restrict__ pos_emb,
    const float* __restrict__ face_emb, const int* __restrict__ face_ids,
    const float* __restrict__ W_nbr, const float* __restrict__ b_nbr,
    const float* __restrict__ W_ql, const float* __restrict__ b_ql,
    const float* __restrict__ W_qg, const float* __restrict__ b_qg,
    float* __restrict__ S, float* __restrict__ qlocal,
    float* __restrict__ qg, float* __restrict__ c01)
{
  __shared__ __align__(16) float qT[4][128][4];   // [wave][dim][sensor]
  const int w = threadIdx.x >> 6, lane = threadIdx.x & 63;
  const int grp = blockIdx.x * 4 + w;
  if (grp >= NSN / 4) return;
  const int n0 = grp * 4;
  #pragma unroll
  for (int si = 0; si < 4; ++si) {
    const int n = n0 + si;
    const int fid = face_ids[n];
    const int e1 = lane + 64;
    qT[w][lane][si] = pos_emb[n * 96 + lane];
    qT[w][e1][si] = (e1 < 96) ? pos_emb[n * 96 + e1] : face_emb[fid * 32 + (e1 - 96)];
  }
  const float bn = b_nbr[lane], bq = b_ql[lane];
  const float bg0 = b_qg[lane], bg1 = b_qg[lane + 64];
  float s[4], ql[4], g0[4], g1[4];
  #pragma unroll
  for (int si = 0; si < 4; ++si) { s[si] = bn; ql[si] = bq; g0[si] = bg0; g1[si] = bg1; }
  #pragma unroll 2
  for (int i = 0; i < 128; ++i) {
    const float wn  = W_nbr[(2 + i) * 64 + lane];
    const float wq  = W_ql[i * 64 + lane];
    const float wg0 = W_qg[i * 128 + lane];
    const float wg1 = W_qg[i * 128 + 64 + lane];
    const float4 qv = *(const float4*)&qT[w][i][0];
    s[0]  += qv.x * wn;  s[1]  += qv.y * wn;  s[2]  += qv.z * wn;  s[3]  += qv.w * wn;
    ql[0] += qv.x * wq;  ql[1] += qv.y * wq;  ql[2] += qv.z * wq;  ql[3] += qv.w * wq;
    g0[0] += qv.x * wg0; g0[1] += qv.y * wg0; g0[2] += qv.z * wg0; g0[3] += qv.w * wg0;
    g1[0] += qv.x * wg1; g1[1] += qv.y * wg1; g1[2] += qv.z * wg1; g1[3] += qv.w * wg1;
  }
  const float wn0 = W_nbr[lane], wn1 = W_nbr[64 + lane];
  #pragma unroll
  for (int si = 0; si < 4; ++si) {
    const int n = n0 + si;
    S[n * 64 + lane] = s[si];
    qlocal[n * 64 + lane] = ql[si];
    qg[n * 128 + lane] = g0[si];
    qg[n * 128 + 64 + lane] = g1[si];
    float p0 = wn0 * ql[si], p1 = wn1 * ql[si];
    #pragma unroll
    for (int o = 32; o; o >>= 1) { p0 += __shfl_xor(p0, o); p1 += __shfl_xor(p1, o); }
    if (lane == 0) { c01[2 * n] = p0; c01[2 * n + 1] = p1; }
  }
}

// ---------------- Kernel B: latent -> K/V (96 rows) ------------------------
__global__ void precompute_latent(const float* __restrict__ latent,
    const float* __restrict__ face_emb,
    const float* __restrict__ W_lat, const float* __restrict__ b_lat,
    const float* __restrict__ W_lf, const float* __restrict__ b_lf,
    const float* __restrict__ W_k, const float* __restrict__ b_k,
    const float* __restrict__ W_v, const float* __restrict__ b_v,
    float* __restrict__ kg, float* __restrict__ vg)
{
  __shared__ __align__(16) float lat[1024];
  __shared__ __align__(16) float kv[128];
  const int bt = blockIdx.x;
  const int t = bt % NT;
  const int o = threadIdx.x;
  for (int i = o; i < 1024; i += 128) lat[i] = latent[bt * 1024 + i];
  __syncthreads();
  float acc = b_lat[o] + b_lf[o];
  #pragma unroll 8
  for (int i = 0; i < 1024; ++i) acc += lat[i] * W_lat[i * 128 + o];
  #pragma unroll
  for (int i = 0; i < 32; ++i) acc += face_emb[t * 32 + i] * W_lf[i * 128 + o];
  kv[o] = acc;
  __syncthreads();
  float kk = b_k[o], vv = b_v[o];
  #pragma unroll 4
  for (int i = 0; i < 128; ++i) {
    const float c = kv[i];
    kk += c * W_k[i * 128 + o];
    vv += c * W_v[i * 128 + o];
  }
  kg[bt * 128 + o] = kk;
  vg[bt * 128 + o] = vv;
}

// ---------------- Main fused kernel: one wave per (b,n), 8 waves/block -----
// NOTE: second __launch_bounds__ arg behaves as blocks/CU on this toolchain
// ((512,4) forced a 64-VGPR cap -> massive scratch spills, round 4).
// (512,2): cap 128 VGPR, 2 blocks/CU = 16 waves/CU, LDS 2x60.4KB fits 160KB.
// Unrolls on the weight loops are CAPPED so the compiler doesn't hoist the
// whole weight stream into registers (round 5: full unroll -> >128 VGPR,
// 35 MB scratch writes).
__launch_bounds__(512, 2)
__global__ void fused_main(const float* __restrict__ x_flat,
    const int* __restrict__ mask, const int* __restrict__ knn,
    const float* __restrict__ Wnbr,
    const float* __restrict__ S, const float* __restrict__ qlocal,
    const float* __restrict__ qg, const float* __restrict__ c01,
    const float* __restrict__ kg, const float* __restrict__ vg,
    const float* __restrict__ Wgo, const float* __restrict__ bgo,
    const float* __restrict__ lng, const float* __restrict__ lnb,
    const float* __restrict__ Wm1, const float* __restrict__ bm1,
    const float* __restrict__ Wm2, const float* __restrict__ bm2,
    float* __restrict__ out)
{
  // WgS4[i2*64+o2] = (Wgo[2i2][2o2], Wgo[2i2+1][2o2], Wgo[2i2][2o2+1], Wgo[2i2+1][2o2+1])
  __shared__ __align__(16) h4 WgS4[64 * 64];        // 32768 B
  // WmT[o*100 + i2] = (Wm1[2i2][o], Wm1[2i2+1][o]) ; stride 100 h2 for bank spread
  __shared__ __align__(16) h2 WmT[64 * 100];        // 25600 B
  __shared__ __align__(16) float qlS[8][64];        // 2048 B -> total 60416 B

  const int tid = threadIdx.x;
  for (int idx = tid; idx < 64 * 64; idx += 512) {
    const int i2 = idx >> 6, o2 = idx & 63;
    const float2 r0 = *(const float2*)(Wgo + (2 * i2) * 128 + 2 * o2);
    const float2 r1 = *(const float2*)(Wgo + (2 * i2 + 1) * 128 + 2 * o2);
    h4 v; v[0] = (_Float16)r0.x; v[1] = (_Float16)r1.x; v[2] = (_Float16)r0.y; v[3] = (_Float16)r1.y;
    WgS4[i2 * 64 + o2] = v;
  }
  for (int idx = tid; idx < 96 * 64; idx += 512) {
    const int i2 = idx >> 6, o = idx & 63;
    h2 v; v[0] = (_Float16)Wm1[(2 * i2) * 64 + o]; v[1] = (_Float16)Wm1[(2 * i2 + 1) * 64 + o];
    WmT[o * 100 + i2] = v;
  }
  __syncthreads();

  const int w = tid >> 6, lane = tid & 63;
  // hoisted per-lane constants
  const float w0 = Wnbr[lane], w1 = Wnbr[64 + lane];
  const float bgo0 = bgo[2 * lane], bgo1 = bgo[2 * lane + 1];
  const float lng_a  = lng[lane],           lnb_a  = lnb[lane];
  const float lng_b0 = lng[64 + 2 * lane],  lnb_b0 = lnb[64 + 2 * lane];
  const float lng_b1 = lng[65 + 2 * lane],  lnb_b1 = lnb[65 + 2 * lane];
  const float bm1_l = bm1[lane], wm2_l = Wm2[lane], bm2_s = bm2[0];

  const int stride = gridDim.x * 8;
  for (int item = blockIdx.x * 8 + w; item < NB * NSN; item += stride) {
    const int b = item / NSN;
    const int n = item - b * NSN;

    // ---- stage per-item vectors ----
    const float ql = qlocal[n * 64 + lane];
    qlS[w][lane] = ql;
    int jv = 0; float x0 = 0.f, x1 = 0.f;
    if (lane < 16) {
      jv = knn[n * 16 + lane];
      const float2 x01 = *(const float2*)(x_flat + (size_t)(b * NSN + jv) * 2);
      x0 = x01.x; x1 = x01.y;
    }

    // ---- Pass 1: KNN logits (4 lanes per neighbor k) ----
    const int k = lane >> 2, d = lane & 3;
    const int jk = __shfl(jv, k);
    const float4* Sr = (const float4*)(S + jk * 64 + d * 16);
    const float4* qr = (const float4*)(&qlS[w][d * 16]);
    float acc = 0.f;
    #pragma unroll
    for (int i = 0; i < 4; ++i) {
      const float4 sv = Sr[i]; const float4 qv = qr[i];
      acc += sv.x * qv.x + sv.y * qv.y + sv.z * qv.z + sv.w * qv.w;
    }
    acc += __shfl_xor(acc, 1); acc += __shfl_xor(acc, 2);
    const float c0 = c01[2 * n], c1 = c01[2 * n + 1];
    const float xk0 = __shfl(x0, k), xk1 = __shfl(x1, k);
    float logit = (acc + xk0 * c0 + xk1 * c1) * 0.125f;
    if (mask[b * NSN + jk] != 0) logit = -10000.0f;
    float mx = logit;
    mx = fmaxf(mx, __shfl_xor(mx, 4));  mx = fmaxf(mx, __shfl_xor(mx, 8));
    mx = fmaxf(mx, __shfl_xor(mx, 16)); mx = fmaxf(mx, __shfl_xor(mx, 32));
    const float e = __expf(logit - mx);
    float s4 = e;
    s4 += __shfl_xor(s4, 4); s4 += __shfl_xor(s4, 8);
    s4 += __shfl_xor(s4, 16); s4 += __shfl_xor(s4, 32);   // = sum over the 16 k
    const float attn = e / s4;
    float ax0 = attn * xk0, ax1 = attn * xk1;
    ax0 += __shfl_xor(ax0, 4); ax0 += __shfl_xor(ax0, 8);
    ax0 += __shfl_xor(ax0, 16); ax0 += __shfl_xor(ax0, 32);
    ax1 += __shfl_xor(ax1, 4); ax1 += __shfl_xor(ax1, 8);
    ax1 += __shfl_xor(ax1, 16); ax1 += __shfl_xor(ax1, 32);

    // ---- Pass 2: local_feat[h] (lane = h), attn/j broadcast via readlane ----
    float lf = ax0 * w0 + ax1 * w1;
    #pragma unroll
    for (int kk = 0; kk < 16; ++kk) {
      const int jr = __builtin_amdgcn_readlane(jv, kk);
      const float aw = rl_f(attn, 4 * kk);
      lf += aw * S[jr * 64 + lane];
    }

    // ---- Phase B: global attention (head h = lane>>4, dims 2l,2l+1) ----
    const float2 q2 = *(const float2*)(qg + n * 128 + 2 * lane);
    const float2* kgb = (const float2*)(kg + b * NT * 128);
    const float2* vgb = (const float2*)(vg + b * NT * 128);
    float gl[NT];
    #pragma unroll
    for (int t = 0; t < NT; ++t) {
      const float2 k2 = kgb[t * 64 + lane];
      float p = q2.x * k2.x + q2.y * k2.y;
      p += __shfl_xor(p, 1); p += __shfl_xor(p, 2);
      p += __shfl_xor(p, 4); p += __shfl_xor(p, 8);
      gl[t] = p * 0.17677669529663687f;   // 1/sqrt(32)
    }
    float gm = gl[0];
    #pragma unroll
    for (int t = 1; t < NT; ++t) gm = fmaxf(gm, gl[t]);
    float gs = 0.f;
    #pragma unroll
    for (int t = 0; t < NT; ++t) { gl[t] = __expf(gl[t] - gm); gs += gl[t]; }
    const float ginv = 1.0f / gs;
    float gfx = 0.f, gfy = 0.f;
    #pragma unroll
    for (int t = 0; t < NT; ++t) {
      const float2 v2 = vgb[t * 64 + lane];
      const float a = gl[t] * ginv;
      gfx += a * v2.x; gfy += a * v2.y;
    }
    h2 gp; gp[0] = (_Float16)gfx; gp[1] = (_Float16)gfy;
    const int gpi = __builtin_bit_cast(int, gp);

    // ---- Phase C: g_out = g_feat @ W_go (+b); lane -> outputs 2l, 2l+1 ----
    float a0 = 0.f, a1 = 0.f;
    #pragma unroll 8
    for (int i2 = 0; i2 < 64; ++i2) {
      const h2 g2 = rl_h2(gpi, i2);
      const h4 wv = WgS4[i2 * 64 + lane];
      const h2 wlo = __builtin_shufflevector(wv, wv, 0, 1);
      const h2 whi = __builtin_shufflevector(wv, wv, 2, 3);
      a0 = fdot2f(g2, wlo, a0);
      a1 = fdot2f(g2, whi, a1);
    }
    const float go0 = a0 + bgo0, go1 = a1 + bgo1;

    // ---- Phase D: LayerNorm over 192 (c[l], c[64+2l], c[65+2l]) ----
    float s1 = lf + go0 + go1;
    float s2 = lf * lf + go0 * go0 + go1 * go1;
    #pragma unroll
    for (int o = 32; o; o >>= 1) { s1 += __shfl_xor(s1, o); s2 += __shfl_xor(s2, o); }
    const float mu  = s1 * (1.0f / 192.0f);
    const float var = s2 * (1.0f / 192.0f) - mu * mu;
    const float rinv = rsqrtf(var + 1e-5f);
    const float n0v = (lf  - mu) * rinv * lng_a  + lnb_a;
    const float n1v = (go0 - mu) * rinv * lng_b0 + lnb_b0;
    const float n2v = (go1 - mu) * rinv * lng_b1 + lnb_b1;
    // pack normed for readlane broadcast: pair m (dims 2m,2m+1) on lane m (m<32);
    // pair 32+l (dims 64+2l,65+2l) on lane l
    const float pl = __shfl(n0v, lane * 2);
    const float ph = __shfl(n0v, lane * 2 + 1);
    h2 lo2; lo2[0] = (_Float16)pl;  lo2[1] = (_Float16)ph;
    h2 hi2; hi2[0] = (_Float16)n1v; hi2[1] = (_Float16)n2v;
    const int clo = __builtin_bit_cast(int, lo2);
    const int chi = __builtin_bit_cast(int, hi2);

    // ---- Phase E: MLP: normed @ W_m1 (+b), GELU(exact), @ W_m2 (+b) ----
    float m1a = bm1_l;
    #pragma unroll 4
    for (int g = 0; g < 24; ++g) {
      const h8 ww = *(const h8*)&WmT[lane * 100 + g * 4];
      const int i2b = g * 4;
      {
        const int i2 = i2b + 0;
        const h2 cc = (i2 < 32) ? rl_h2(clo, i2) : rl_h2(chi, i2 - 32);
        const h2 wp = __builtin_shufflevector(ww, ww, 0, 1);
        m1a = fdot2f(cc, wp, m1a);
      }
      {
        const int i2 = i2b + 1;
        const h2 cc = (i2 < 32) ? rl_h2(clo, i2) : rl_h2(chi, i2 - 32);
        const h2 wp = __builtin_shufflevector(ww, ww, 2, 3);
        m1a = fdot2f(cc, wp, m1a);
      }
      {
        const int i2 = i2b + 2;
        const h2 cc = (i2 < 32) ? rl_h2(clo, i2) : rl_h2(chi, i2 - 32);
        const h2 wp = __builtin_shufflevector(ww, ww, 4, 5);
        m1a = fdot2f(cc, wp, m1a);
      }
      {
        const int i2 = i2b + 3;
        const h2 cc = (i2 < 32) ? rl_h2(clo, i2) : rl_h2(chi, i2 - 32);
        const h2 wp = __builtin_shufflevector(ww, ww, 6, 7);
        m1a = fdot2f(cc, wp, m1a);
      }
    }
    const float gelu = 0.5f * m1a * (1.0f + erff(m1a * 0.7071067811865476f));
    float pr = gelu * wm2_l;
    #pragma unroll
    for (int o = 32; o; o >>= 1) pr += __shfl_xor(pr, o);
    float res = pr + bm2_s;
    if (mask[item] == 0) res = 0.f;   // preds * (mask != 0)
    if (lane == 0) out[item] = res;
  }
}

extern "C" void kernel_launch(void* const* d_in, const int* in_sizes, int n_in,
                              void* d_out, int out_size, void* d_ws, size_t ws_size,
                              hipStream_t stream) {
  (void)in_sizes; (void)n_in; (void)out_size; (void)ws_size;
  const float* x_flat   = (const float*)d_in[0];
  const float* latent   = (const float*)d_in[1];
  const float* pos_emb  = (const float*)d_in[2];
  const float* face_emb = (const float*)d_in[3];
  const float* W_nbr = (const float*)d_in[4];
  const float* b_nbr = (const float*)d_in[5];
  const float* W_ql  = (const float*)d_in[6];
  const float* b_ql  = (const float*)d_in[7];
  const float* W_lat = (const float*)d_in[8];
  const float* b_lat = (const float*)d_in[9];
  const float* W_lf  = (const float*)d_in[10];
  const float* b_lf  = (const float*)d_in[11];
  const float* W_qg  = (const float*)d_in[12];
  const float* b_qg  = (const float*)d_in[13];
  const float* W_k   = (const float*)d_in[14];
  const float* b_k   = (const float*)d_in[15];
  const float* W_v   = (const float*)d_in[16];
  const float* b_v   = (const float*)d_in[17];
  const float* W_go  = (const float*)d_in[18];
  const float* b_go  = (const float*)d_in[19];
  const float* ln_g  = (const float*)d_in[20];
  const float* ln_b  = (const float*)d_in[21];
  const float* W_m1  = (const float*)d_in[22];
  const float* b_m1  = (const float*)d_in[23];
  const float* W_m2  = (const float*)d_in[24];
  const float* b_m2  = (const float*)d_in[25];
  const int* mask     = (const int*)d_in[26];
  const int* knn      = (const int*)d_in[27];
  const int* face_ids = (const int*)d_in[28];
  float* out = (float*)d_out;

  float* ws = (float*)d_ws;
  float* S      = ws;  ws += NSN * 64;
  float* qlocal = ws;  ws += NSN * 64;
  float* qgb    = ws;  ws += NSN * 128;
  float* c01    = ws;  ws += NSN * 2;
  float* kgb    = ws;  ws += NB * NT * 128;
  float* vgb    = ws;  ws += NB * NT * 128;

  precompute_sensor<<<298, 256, 0, stream>>>(pos_emb, face_emb, face_ids,
      W_nbr, b_nbr, W_ql, b_ql, W_qg, b_qg, S, qlocal, qgb, c01);
  precompute_latent<<<96, 128, 0, stream>>>(latent, face_emb, W_lat, b_lat,
      W_lf, b_lf, W_k, b_k, W_v, b_v, kgb, vgb);
  fused_main<<<512, 512, 0, stream>>>(x_flat, mask, knn, W_nbr,
      S, qlocal, qgb, c01, kgb, vgb, W_go, b_go, ln_g, ln_b,
      W_m1, b_m1, W_m2, b_m2, out);
}

// Round 7
// 339.088 us; speedup vs baseline: 2.1152x; 1.0994x over previous
//
#include <hip/hip_runtime.h>
#include <math.h>

#define NSN 4760
#define KNN 16
#define NT 6
#define NB 16
#define NGB 595   // n-groups per batch: 595*8 = 4760

__device__ __forceinline__ float rl_f(float v, int lane) {
  return __builtin_bit_cast(float, __builtin_amdgcn_readlane(__builtin_bit_cast(int, v), lane));
}

// ---------------- Kernel A: per-sensor precompute (batch independent) ------
// S[n]      = query[n] @ W_nbr[2:,:] + b_nbr          (64)
// qlocal[n] = query[n] @ W_ql + b_ql                  (64)
// qg[n]     = query[n] @ W_qg + b_qg                  (128)
// c01[n]    = { W_nbr[0]*qlocal[n], W_nbr[1]*qlocal[n] }
// SM[n][o]  = sum_h S[n][h]*ln_g[h]*W_m1[h][o]        (64)  <- LN/MLP folding
__global__ void precompute_sensor(const float* __restrict__ pos_emb,
    const float* __restrict__ face_emb, const int* __restrict__ face_ids,
    const float* __restrict__ W_nbr, const float* __restrict__ b_nbr,
    const float* __restrict__ W_ql, const float* __restrict__ b_ql,
    const float* __restrict__ W_qg, const float* __restrict__ b_qg,
    const float* __restrict__ W_m1, const float* __restrict__ ln_g,
    float* __restrict__ S, float* __restrict__ qlocal,
    float* __restrict__ qg, float* __restrict__ c01, float* __restrict__ SM)
{
  __shared__ __align__(16) float qT[4][128][4];   // [wave][dim][sensor]
  const int w = threadIdx.x >> 6, lane = threadIdx.x & 63;
  const int grp = blockIdx.x * 4 + w;
  if (grp >= NSN / 4) return;
  const int n0 = grp * 4;
  #pragma unroll
  for (int si = 0; si < 4; ++si) {
    const int n = n0 + si;
    const int fid = face_ids[n];
    const int e1 = lane + 64;
    qT[w][lane][si] = pos_emb[n * 96 + lane];
    qT[w][e1][si] = (e1 < 96) ? pos_emb[n * 96 + e1] : face_emb[fid * 32 + (e1 - 96)];
  }
  const float bn = b_nbr[lane], bq = b_ql[lane];
  const float bg0 = b_qg[lane], bg1 = b_qg[lane + 64];
  float s[4], ql[4], g0[4], g1[4];
  #pragma unroll
  for (int si = 0; si < 4; ++si) { s[si] = bn; ql[si] = bq; g0[si] = bg0; g1[si] = bg1; }
  #pragma unroll 2
  for (int i = 0; i < 128; ++i) {
    const float wn  = W_nbr[(2 + i) * 64 + lane];
    const float wq  = W_ql[i * 64 + lane];
    const float wg0 = W_qg[i * 128 + lane];
    const float wg1 = W_qg[i * 128 + 64 + lane];
    const float4 qv = *(const float4*)&qT[w][i][0];
    s[0]  += qv.x * wn;  s[1]  += qv.y * wn;  s[2]  += qv.z * wn;  s[3]  += qv.w * wn;
    ql[0] += qv.x * wq;  ql[1] += qv.y * wq;  ql[2] += qv.z * wq;  ql[3] += qv.w * wq;
    g0[0] += qv.x * wg0; g0[1] += qv.y * wg0; g0[2] += qv.z * wg0; g0[3] += qv.w * wg0;
    g1[0] += qv.x * wg1; g1[1] += qv.y * wg1; g1[2] += qv.z * wg1; g1[3] += qv.w * wg1;
  }
  const float wn0 = W_nbr[lane], wn1 = W_nbr[64 + lane];
  #pragma unroll
  for (int si = 0; si < 4; ++si) {
    const int n = n0 + si;
    S[n * 64 + lane] = s[si];
    qlocal[n * 64 + lane] = ql[si];
    qg[n * 128 + lane] = g0[si];
    qg[n * 128 + 64 + lane] = g1[si];
    float p0 = wn0 * ql[si], p1 = wn1 * ql[si];
    #pragma unroll
    for (int o = 32; o; o >>= 1) { p0 += __shfl_xor(p0, o); p1 += __shfl_xor(p1, o); }
    if (lane == 0) { c01[2 * n] = p0; c01[2 * n + 1] = p1; }
  }
  // ---- SM: (S .* ln_g[0:64]) @ W_m1[0:64,:]  (wave-private qT reuse) ----
  const float gl = ln_g[lane];
  #pragma unroll
  for (int si = 0; si < 4; ++si) qT[w][lane][si] = s[si] * gl;
  float sm0 = 0.f, sm1 = 0.f, sm2 = 0.f, sm3 = 0.f;
  #pragma unroll 4
  for (int h = 0; h < 64; ++h) {
    const float w1v = W_m1[h * 64 + lane];
    const float4 sv = *(const float4*)&qT[w][h][0];
    sm0 += sv.x * w1v; sm1 += sv.y * w1v; sm2 += sv.z * w1v; sm3 += sv.w * w1v;
  }
  SM[(n0 + 0) * 64 + lane] = sm0;
  SM[(n0 + 1) * 64 + lane] = sm1;
  SM[(n0 + 2) * 64 + lane] = sm2;
  SM[(n0 + 3) * 64 + lane] = sm3;
}

// ---------------- Kernel B: latent -> K, VW, VWM (96 blocks) ---------------
// kv = latent@W_lat + b_lat + face_emb[t]@W_lf + b_lf
// kg = kv@W_k + b_k
// VW[b,t,h,o]  = sum_{i in head h} (kv@W_v+b_v)[i] * W_go[i][o]   (o<128)
// VWM[b,t,h,o] = sum_{i<128} VW[b,t,h,i]*ln_g[64+i]*W_m1[64+i][o] (o<64)
__global__ void precompute_latent(const float* __restrict__ latent,
    const float* __restrict__ face_emb,
    const float* __restrict__ W_lat, const float* __restrict__ b_lat,
    const float* __restrict__ W_lf, const float* __restrict__ b_lf,
    const float* __restrict__ W_k, const float* __restrict__ b_k,
    const float* __restrict__ W_v, const float* __restrict__ b_v,
    const float* __restrict__ W_go, const float* __restrict__ W_m1,
    const float* __restrict__ ln_g,
    float* __restrict__ kg, float* __restrict__ VW, float* __restrict__ VWM)
{
  __shared__ __align__(16) float lat[1024];
  __shared__ __align__(16) float kv[128];
  __shared__ __align__(16) float vrow[128];
  __shared__ __align__(16) float vwl[4][128];
  __shared__ __align__(16) float ghl[128];
  const int bt = blockIdx.x;
  const int t = bt % NT;
  const int o = threadIdx.x;
  for (int i = o; i < 1024; i += 128) lat[i] = latent[bt * 1024 + i];
  ghl[o] = ln_g[64 + o];
  __syncthreads();
  float acc = b_lat[o] + b_lf[o];
  #pragma unroll 8
  for (int i = 0; i < 1024; ++i) acc += lat[i] * W_lat[i * 128 + o];
  #pragma unroll
  for (int i = 0; i < 32; ++i) acc += face_emb[t * 32 + i] * W_lf[i * 128 + o];
  kv[o] = acc;
  __syncthreads();
  float kk = b_k[o], vv = b_v[o];
  #pragma unroll 4
  for (int i = 0; i < 128; ++i) {
    const float c = kv[i];
    kk += c * W_k[i * 128 + o];
    vv += c * W_v[i * 128 + o];
  }
  kg[bt * 128 + o] = kk;
  vrow[o] = vv;
  __syncthreads();
  #pragma unroll
  for (int h = 0; h < 4; ++h) {
    float a = 0.f;
    #pragma unroll 8
    for (int i = 0; i < 32; ++i)
      a += vrow[h * 32 + i] * W_go[(h * 32 + i) * 128 + o];
    VW[(bt * 4 + h) * 128 + o] = a;
    vwl[h][o] = a;
  }
  __syncthreads();
  if (o < 64) {
    #pragma unroll
    for (int h = 0; h < 4; ++h) {
      float m = 0.f;
      #pragma unroll 4
      for (int i = 0; i < 128; ++i)
        m += vwl[h][i] * ghl[i] * W_m1[(64 + i) * 64 + o];
      VWM[(bt * 4 + h) * 64 + o] = m;
    }
  }
}

// ---------------- Kernel C: small fold constants (3 blocks x 64) -----------
// CONSTS: [0:64) WA, [64:128) WB, [128:192) G, [192:256) P, [256:320) C1
__global__ void precompute_consts(const float* __restrict__ W_nbr,
    const float* __restrict__ ln_g, const float* __restrict__ ln_b,
    const float* __restrict__ W_m1, const float* __restrict__ b_m1,
    const float* __restrict__ b_go, float* __restrict__ C)
{
  const int o = threadIdx.x;
  if (blockIdx.x == 0) {
    float wa = 0.f, wb = 0.f;
    #pragma unroll 4
    for (int h = 0; h < 64; ++h) {
      const float gw = ln_g[h] * W_m1[h * 64 + o];
      wa += W_nbr[h] * gw;
      wb += W_nbr[64 + h] * gw;
    }
    C[o] = wa; C[64 + o] = wb;
  } else if (blockIdx.x == 1) {
    float g = 0.f, p = 0.f;
    #pragma unroll 4
    for (int d = 0; d < 192; ++d) {
      const float w1 = W_m1[d * 64 + o];
      g += ln_g[d] * w1;
      p += ln_b[d] * w1;
    }
    C[128 + o] = g; C[192 + o] = p + b_m1[o];
  } else {
    float c1 = 0.f;
    #pragma unroll 4
    for (int i = 0; i < 128; ++i)
      c1 += b_go[i] * ln_g[64 + i] * W_m1[(64 + i) * 64 + o];
    C[256 + o] = c1;
  }
}

// ---------------- Main fused kernel: block = (b, 8 n's), wave = one item ---
// All heavy per-item matvecs replaced by gathered/folded tables:
//   g_out = sum a[h,t]*VW ;  m1 = rinv*(L + M + C1 - mu*G) + P
//   L = sum_k attn_k*SM[j_k] + ax0*WA + ax1*WB ; M = sum a[h,t]*VWM
__launch_bounds__(512, 2)
__global__ void fused_main(const float* __restrict__ x_flat,
    const int* __restrict__ mask, const int* __restrict__ knn,
    const float* __restrict__ Wnbr,
    const float* __restrict__ S, const float* __restrict__ qlocal,
    const float* __restrict__ qg, const float* __restrict__ c01,
    const float* __restrict__ kg, const float* __restrict__ SM,
    const float* __restrict__ VW, const float* __restrict__ VWM,
    const float* __restrict__ CONSTS,
    const float* __restrict__ bgo, const float* __restrict__ Wm2,
    const float* __restrict__ bm2, float* __restrict__ out)
{
  __shared__ __align__(16) float VWl[NT * 4 * 128];   // 12 KB
  __shared__ __align__(16) float VWMl[NT * 4 * 64];   // 6 KB
  __shared__ __align__(16) float kgl[NT * 128];       // 3 KB
  __shared__ __align__(16) float qlS[8][64];          // 2 KB  -> 23.5 KB total

  const int tid = threadIdx.x;
  const int b = blockIdx.x / NGB;
  const int ng = blockIdx.x - b * NGB;

  {
    const float* vwb = VW + b * (NT * 4 * 128);
    for (int i = tid; i < NT * 4 * 128; i += 512) VWl[i] = vwb[i];
    const float* vwmb = VWM + b * (NT * 4 * 64);
    for (int i = tid; i < NT * 4 * 64; i += 512) VWMl[i] = vwmb[i];
    const float* kgb = kg + b * (NT * 128);
    for (int i = tid; i < NT * 128; i += 512) kgl[i] = kgb[i];
  }
  __syncthreads();

  const int w = tid >> 6, lane = tid & 63;
  const int n = ng * 8 + w;
  const int item = b * NSN + n;

  // per-lane folded constants (L2-hot broadcasts)
  const float wa  = CONSTS[lane],       wbc = CONSTS[64 + lane];
  const float cg  = CONSTS[128 + lane], cp  = CONSTS[192 + lane];
  const float cc1 = CONSTS[256 + lane];
  const float w0 = Wnbr[lane], w1 = Wnbr[64 + lane];
  const float bgo0 = bgo[2 * lane], bgo1 = bgo[2 * lane + 1];
  const float wm2 = Wm2[lane], bm2s = bm2[0];
  const float c0 = c01[2 * n], c1 = c01[2 * n + 1];
  const int mself = mask[item];

  const float ql = qlocal[n * 64 + lane];
  qlS[w][lane] = ql;
  int jv = 0, mk = 0; float x0 = 0.f, x1 = 0.f;
  if (lane < 16) {
    jv = knn[n * 16 + lane];
    const float2 x01 = *(const float2*)(x_flat + (size_t)(b * NSN + jv) * 2);
    x0 = x01.x; x1 = x01.y;
    mk = mask[b * NSN + jv];
  }

  // ---- Pass 1: KNN logits (4 lanes per neighbor k) ----
  const int k = lane >> 2, d = lane & 3;
  const int jk = __shfl(jv, k);
  const float4* Sr = (const float4*)(S + jk * 64 + d * 16);
  const float4* qr = (const float4*)(&qlS[w][d * 16]);
  float acc = 0.f;
  #pragma unroll
  for (int i = 0; i < 4; ++i) {
    const float4 sv = Sr[i]; const float4 qv = qr[i];
    acc += sv.x * qv.x + sv.y * qv.y + sv.z * qv.z + sv.w * qv.w;
  }
  acc += __shfl_xor(acc, 1); acc += __shfl_xor(acc, 2);
  const float xk0 = __shfl(x0, k), xk1 = __shfl(x1, k);
  const int mkk = __shfl(mk, k);
  float logit = (acc + xk0 * c0 + xk1 * c1) * 0.125f;
  if (mkk != 0) logit = -10000.0f;
  float mx = logit;
  mx = fmaxf(mx, __shfl_xor(mx, 4));  mx = fmaxf(mx, __shfl_xor(mx, 8));
  mx = fmaxf(mx, __shfl_xor(mx, 16)); mx = fmaxf(mx, __shfl_xor(mx, 32));
  const float e = __expf(logit - mx);
  float s4 = e;
  s4 += __shfl_xor(s4, 4); s4 += __shfl_xor(s4, 8);
  s4 += __shfl_xor(s4, 16); s4 += __shfl_xor(s4, 32);
  const float attn = e / s4;
  float ax0 = attn * xk0, ax1 = attn * xk1;
  ax0 += __shfl_xor(ax0, 4); ax0 += __shfl_xor(ax0, 8);
  ax0 += __shfl_xor(ax0, 16); ax0 += __shfl_xor(ax0, 32);
  ax1 += __shfl_xor(ax1, 4); ax1 += __shfl_xor(ax1, 8);
  ax1 += __shfl_xor(ax1, 16); ax1 += __shfl_xor(ax1, 32);

  // ---- lf (lane=h) and L (lane=o) via the same 16 row-gathers ----
  float lf = ax0 * w0 + ax1 * w1;
  float L  = ax0 * wa + ax1 * wbc;
  #pragma unroll 4
  for (int kk = 0; kk < 16; ++kk) {
    const int jr = __builtin_amdgcn_readlane(jv, kk);
    const float aw = rl_f(attn, 4 * kk);
    lf += aw * S[jr * 64 + lane];
    L  += aw * SM[jr * 64 + lane];
  }

  // ---- global attention logits (head h = lane>>4, dims 2l,2l+1) ----
  const float2 q2 = *(const float2*)(qg + n * 128 + 2 * lane);
  float av[NT];
  #pragma unroll
  for (int t = 0; t < NT; ++t) {
    const float2 k2 = *(const float2*)&kgl[t * 128 + 2 * lane];
    float p = q2.x * k2.x + q2.y * k2.y;
    p += __shfl_xor(p, 1); p += __shfl_xor(p, 2);
    p += __shfl_xor(p, 4); p += __shfl_xor(p, 8);
    av[t] = p * 0.17677669529663687f;   // 1/sqrt(32)
  }
  float gm = av[0];
  #pragma unroll
  for (int t = 1; t < NT; ++t) gm = fmaxf(gm, av[t]);
  float gs = 0.f;
  #pragma unroll
  for (int t = 0; t < NT; ++t) { av[t] = __expf(av[t] - gm); gs += av[t]; }
  const float ginv = 1.0f / gs;
  #pragma unroll
  for (int t = 0; t < NT; ++t) av[t] *= ginv;

  // ---- g_out (lane -> outputs 2l,2l+1) and M (lane -> o) from tables ----
  float g0 = bgo0, g1 = bgo1, M = 0.f;
  #pragma unroll
  for (int t = 0; t < NT; ++t) {
    #pragma unroll
    for (int h = 0; h < 4; ++h) {
      const float a = rl_f(av[t], 16 * h);
      const float2 vw = *(const float2*)&VWl[(t * 4 + h) * 128 + 2 * lane];
      g0 += a * vw.x; g1 += a * vw.y;
      M += a * VWMl[(t * 4 + h) * 64 + lane];
    }
  }

  // ---- LayerNorm stats over 192 (lane covers lf[lane], g[2l], g[2l+1]) ----
  float s1 = lf + g0 + g1;
  float s2 = lf * lf + g0 * g0 + g1 * g1;
  #pragma unroll
  for (int o = 32; o; o >>= 1) { s1 += __shfl_xor(s1, o); s2 += __shfl_xor(s2, o); }
  const float mu  = s1 * (1.0f / 192.0f);
  const float var = s2 * (1.0f / 192.0f) - mu * mu;
  const float rinv = rsqrtf(var + 1e-5f);

  // ---- folded MLP: m1 -> GELU -> dot W_m2 ----
  const float m1 = rinv * (L + M + cc1 - mu * cg) + cp;
  const float gelu = 0.5f * m1 * (1.0f + erff(m1 * 0.7071067811865476f));
  float pr = gelu * wm2;
  #pragma unroll
  for (int o = 32; o; o >>= 1) pr += __shfl_xor(pr, o);
  float res = pr + bm2s;
  if (mself == 0) res = 0.f;
  if (lane == 0) out[item] = res;
}

extern "C" void kernel_launch(void* const* d_in, const int* in_sizes, int n_in,
                              void* d_out, int out_size, void* d_ws, size_t ws_size,
                              hipStream_t stream) {
  (void)in_sizes; (void)n_in; (void)out_size; (void)ws_size;
  const float* x_flat   = (const float*)d_in[0];
  const float* latent   = (const float*)d_in[1];
  const float* pos_emb  = (const float*)d_in[2];
  const float* face_emb = (const float*)d_in[3];
  const float* W_nbr = (const float*)d_in[4];
  const float* b_nbr = (const float*)d_in[5];
  const float* W_ql  = (const float*)d_in[6];
  const float* b_ql  = (const float*)d_in[7];
  const float* W_lat = (const float*)d_in[8];
  const float* b_lat = (const float*)d_in[9];
  const float* W_lf  = (const float*)d_in[10];
  const float* b_lf  = (const float*)d_in[11];
  const float* W_qg  = (const float*)d_in[12];
  const float* b_qg  = (const float*)d_in[13];
  const float* W_k   = (const float*)d_in[14];
  const float* b_k   = (const float*)d_in[15];
  const float* W_v   = (const float*)d_in[16];
  const float* b_v   = (const float*)d_in[17];
  const float* W_go  = (const float*)d_in[18];
  const float* b_go  = (const float*)d_in[19];
  const float* ln_g  = (const float*)d_in[20];
  const float* ln_b  = (const float*)d_in[21];
  const float* W_m1  = (const float*)d_in[22];
  const float* b_m1  = (const float*)d_in[23];
  const float* W_m2  = (const float*)d_in[24];
  const float* b_m2  = (const float*)d_in[25];
  const int* mask     = (const int*)d_in[26];
  const int* knn      = (const int*)d_in[27];
  const int* face_ids = (const int*)d_in[28];
  float* out = (float*)d_out;

  float* ws = (float*)d_ws;
  float* S      = ws;  ws += NSN * 64;
  float* qlocal = ws;  ws += NSN * 64;
  float* qgb    = ws;  ws += NSN * 128;
  float* c01    = ws;  ws += NSN * 2;
  float* SMt    = ws;  ws += NSN * 64;
  float* kgb    = ws;  ws += NB * NT * 128;
  float* VWt    = ws;  ws += NB * NT * 4 * 128;
  float* VWMt   = ws;  ws += NB * NT * 4 * 64;
  float* CONSTS = ws;  ws += 5 * 64;

  precompute_sensor<<<298, 256, 0, stream>>>(pos_emb, face_emb, face_ids,
      W_nbr, b_nbr, W_ql, b_ql, W_qg, b_qg, W_m1, ln_g,
      S, qlocal, qgb, c01, SMt);
  precompute_latent<<<NB * NT, 128, 0, stream>>>(latent, face_emb,
      W_lat, b_lat, W_lf, b_lf, W_k, b_k, W_v, b_v, W_go, W_m1, ln_g,
      kgb, VWt, VWMt);
  precompute_consts<<<3, 64, 0, stream>>>(W_nbr, ln_g, ln_b, W_m1, b_m1,
      b_go, CONSTS);
  fused_main<<<NB * NGB, 512, 0, stream>>>(x_flat, mask, knn, W_nbr,
      S, qlocal, qgb, c01, kgb, SMt, VWt, VWMt, CONSTS,
      b_go, W_m2, b_m2, out);
}

// Round 8
// 320.874 us; speedup vs baseline: 2.2353x; 1.0568x over previous
//
#include <hip/hip_runtime.h>
#include <math.h>

#define NSN 4760
#define KNN 16
#define NT 6
#define NB 16
#define NGB 595   // n-groups per batch: 595*8 = 4760

__device__ __forceinline__ float rl_f(float v, int lane) {
  return __builtin_bit_cast(float, __builtin_amdgcn_readlane(__builtin_bit_cast(int, v), lane));
}

// ---------------- Kernel A: per-sensor precompute (batch independent) ------
// S[n]      = query[n] @ W_nbr[2:,:] + b_nbr          (64)
// qlocal[n] = query[n] @ W_ql + b_ql                  (64)
// qg[n]     = query[n] @ W_qg + b_qg                  (128)
// c01[n]    = { W_nbr[0]*qlocal[n], W_nbr[1]*qlocal[n] }
// SS[n][h]  = (S[n][h], SM[n][h]) packed float2, SM = (S.*ln_g[:64])@W_m1[:64]
// 512-thread blocks, 149 blocks (<=256 CUs -> no 2-block serialization tail)
__global__ void precompute_sensor(const float* __restrict__ pos_emb,
    const float* __restrict__ face_emb, const int* __restrict__ face_ids,
    const float* __restrict__ W_nbr, const float* __restrict__ b_nbr,
    const float* __restrict__ W_ql, const float* __restrict__ b_ql,
    const float* __restrict__ W_qg, const float* __restrict__ b_qg,
    const float* __restrict__ W_m1, const float* __restrict__ ln_g,
    float* __restrict__ S, float* __restrict__ qlocal,
    float* __restrict__ qg, float* __restrict__ c01, float2* __restrict__ SS)
{
  __shared__ __align__(16) float qT[8][128][4];   // [wave][dim][sensor]
  const int w = threadIdx.x >> 6, lane = threadIdx.x & 63;
  const int grp = blockIdx.x * 8 + w;
  if (grp >= NSN / 4) return;
  const int n0 = grp * 4;
  #pragma unroll
  for (int si = 0; si < 4; ++si) {
    const int n = n0 + si;
    const int fid = face_ids[n];
    const int e1 = lane + 64;
    qT[w][lane][si] = pos_emb[n * 96 + lane];
    qT[w][e1][si] = (e1 < 96) ? pos_emb[n * 96 + e1] : face_emb[fid * 32 + (e1 - 96)];
  }
  const float bn = b_nbr[lane], bq = b_ql[lane];
  const float bg0 = b_qg[lane], bg1 = b_qg[lane + 64];
  float s[4], ql[4], g0[4], g1[4];
  #pragma unroll
  for (int si = 0; si < 4; ++si) { s[si] = bn; ql[si] = bq; g0[si] = bg0; g1[si] = bg1; }
  #pragma unroll 2
  for (int i = 0; i < 128; ++i) {
    const float wn  = W_nbr[(2 + i) * 64 + lane];
    const float wq  = W_ql[i * 64 + lane];
    const float wg0 = W_qg[i * 128 + lane];
    const float wg1 = W_qg[i * 128 + 64 + lane];
    const float4 qv = *(const float4*)&qT[w][i][0];
    s[0]  += qv.x * wn;  s[1]  += qv.y * wn;  s[2]  += qv.z * wn;  s[3]  += qv.w * wn;
    ql[0] += qv.x * wq;  ql[1] += qv.y * wq;  ql[2] += qv.z * wq;  ql[3] += qv.w * wq;
    g0[0] += qv.x * wg0; g0[1] += qv.y * wg0; g0[2] += qv.z * wg0; g0[3] += qv.w * wg0;
    g1[0] += qv.x * wg1; g1[1] += qv.y * wg1; g1[2] += qv.z * wg1; g1[3] += qv.w * wg1;
  }
  const float wn0 = W_nbr[lane], wn1 = W_nbr[64 + lane];
  #pragma unroll
  for (int si = 0; si < 4; ++si) {
    const int n = n0 + si;
    S[n * 64 + lane] = s[si];
    qlocal[n * 64 + lane] = ql[si];
    qg[n * 128 + lane] = g0[si];
    qg[n * 128 + 64 + lane] = g1[si];
    float p0 = wn0 * ql[si], p1 = wn1 * ql[si];
    #pragma unroll
    for (int o = 32; o; o >>= 1) { p0 += __shfl_xor(p0, o); p1 += __shfl_xor(p1, o); }
    if (lane == 0) { c01[2 * n] = p0; c01[2 * n + 1] = p1; }
  }
  // ---- SM: (S .* ln_g[0:64]) @ W_m1[0:64,:]  (wave-private qT reuse) ----
  const float gl = ln_g[lane];
  #pragma unroll
  for (int si = 0; si < 4; ++si) qT[w][lane][si] = s[si] * gl;
  float sm0 = 0.f, sm1 = 0.f, sm2 = 0.f, sm3 = 0.f;
  #pragma unroll 4
  for (int h = 0; h < 64; ++h) {
    const float w1v = W_m1[h * 64 + lane];
    const float4 sv = *(const float4*)&qT[w][h][0];
    sm0 += sv.x * w1v; sm1 += sv.y * w1v; sm2 += sv.z * w1v; sm3 += sv.w * w1v;
  }
  SS[(n0 + 0) * 64 + lane] = make_float2(s[0], sm0);
  SS[(n0 + 1) * 64 + lane] = make_float2(s[1], sm1);
  SS[(n0 + 2) * 64 + lane] = make_float2(s[2], sm2);
  SS[(n0 + 3) * 64 + lane] = make_float2(s[3], sm3);
}

// ---------------- Kernel B: latent -> K, TBL (96 blocks) + consts (1 blk) --
// kv = latent@W_lat + b_lat + face_emb[t]@W_lf + b_lf ; kg = kv@W_k + b_k
// VW[h][o]  = sum_{i in head h} (kv@W_v+b_v)[i] * W_go[i][o]     (o<128)
// VWM[h][o] = sum_{i<128} VW[h][i]*ln_g[64+i]*W_m1[64+i][o]      (o<64)
// TBL[(bt*4+h)*64+o] = (VW[h][2o], VW[h][2o+1], VWM[h][o], 0)
// block NB*NT: CONSTS [0:64) WA [64:128) WB [128:192) G [192:256) P [256:320) C1
__global__ void precompute_latent(const float* __restrict__ latent,
    const float* __restrict__ face_emb,
    const float* __restrict__ W_lat, const float* __restrict__ b_lat,
    const float* __restrict__ W_lf, const float* __restrict__ b_lf,
    const float* __restrict__ W_k, const float* __restrict__ b_k,
    const float* __restrict__ W_v, const float* __restrict__ b_v,
    const float* __restrict__ W_go, const float* __restrict__ W_m1,
    const float* __restrict__ ln_g, const float* __restrict__ ln_b,
    const float* __restrict__ b_m1, const float* __restrict__ W_nbr,
    const float* __restrict__ b_go,
    float* __restrict__ kg, float4* __restrict__ TBL, float* __restrict__ C)
{
  const int bt = blockIdx.x;
  const int o = threadIdx.x;
  if (bt == NB * NT) {            // fold constants
    if (o < 64) {
      float wa = 0.f, wb = 0.f;
      #pragma unroll 4
      for (int h = 0; h < 64; ++h) {
        const float gw = ln_g[h] * W_m1[h * 64 + o];
        wa += W_nbr[h] * gw;
        wb += W_nbr[64 + h] * gw;
      }
      C[o] = wa; C[64 + o] = wb;
      float g = 0.f, p = 0.f;
      #pragma unroll 4
      for (int d = 0; d < 192; ++d) {
        const float w1 = W_m1[d * 64 + o];
        g += ln_g[d] * w1;
        p += ln_b[d] * w1;
      }
      C[128 + o] = g; C[192 + o] = p + b_m1[o];
      float c1 = 0.f;
      #pragma unroll 4
      for (int i = 0; i < 128; ++i)
        c1 += b_go[i] * ln_g[64 + i] * W_m1[(64 + i) * 64 + o];
      C[256 + o] = c1;
    }
    return;
  }
  __shared__ __align__(16) float lat[1024];
  __shared__ __align__(16) float kv[128];
  __shared__ __align__(16) float vrow[128];
  __shared__ __align__(16) float vwl[4][128];
  __shared__ __align__(16) float ghl[128];
  const int t = bt % NT;
  for (int i = o; i < 1024; i += 128) lat[i] = latent[bt * 1024 + i];
  ghl[o] = ln_g[64 + o];
  __syncthreads();
  float acc = b_lat[o] + b_lf[o];
  #pragma unroll 8
  for (int i = 0; i < 1024; ++i) acc += lat[i] * W_lat[i * 128 + o];
  #pragma unroll
  for (int i = 0; i < 32; ++i) acc += face_emb[t * 32 + i] * W_lf[i * 128 + o];
  kv[o] = acc;
  __syncthreads();
  float kk = b_k[o], vv = b_v[o];
  #pragma unroll 4
  for (int i = 0; i < 128; ++i) {
    const float c = kv[i];
    kk += c * W_k[i * 128 + o];
    vv += c * W_v[i * 128 + o];
  }
  kg[bt * 128 + o] = kk;
  vrow[o] = vv;
  __syncthreads();
  #pragma unroll
  for (int h = 0; h < 4; ++h) {
    float a = 0.f;
    #pragma unroll 8
    for (int i = 0; i < 32; ++i)
      a += vrow[h * 32 + i] * W_go[(h * 32 + i) * 128 + o];
    vwl[h][o] = a;
  }
  __syncthreads();
  if (o < 64) {
    #pragma unroll
    for (int h = 0; h < 4; ++h) {
      float m = 0.f;
      #pragma unroll 4
      for (int i = 0; i < 128; ++i)
        m += vwl[h][i] * ghl[i] * W_m1[(64 + i) * 64 + o];
      TBL[(bt * 4 + h) * 64 + o] =
          make_float4(vwl[h][2 * o], vwl[h][2 * o + 1], m, 0.f);
    }
  }
}

// ---------------- Main fused kernel: block = (b, 8 n's), wave = one item ---
//   g_out = sum a[h,t]*TBL.xy ;  m1 = rinv*(L + M + C1 - mu*G) + P
//   L = sum_k attn_k*SS.y[j_k] + ax0*WA + ax1*WB ; M = sum a[h,t]*TBL.z
__launch_bounds__(512, 2)
__global__ void fused_main(const float* __restrict__ x_flat,
    const int* __restrict__ mask, const int* __restrict__ knn,
    const float* __restrict__ Wnbr,
    const float* __restrict__ S, const float* __restrict__ qlocal,
    const float* __restrict__ qg, const float* __restrict__ c01,
    const float* __restrict__ kg, const float2* __restrict__ SS,
    const float4* __restrict__ TBL, const float* __restrict__ CONSTS,
    const float* __restrict__ bgo, const float* __restrict__ Wm2,
    const float* __restrict__ bm2, float* __restrict__ out)
{
  __shared__ __align__(16) float4 TBLl[NT * 4 * 64];  // 24 KB
  __shared__ __align__(16) float kgl[NT * 128];       // 3 KB
  __shared__ __align__(16) float qlS[8][64];          // 2 KB -> 29 KB total

  const int tid = threadIdx.x;
  const int b = blockIdx.x / NGB;
  const int ng = blockIdx.x - b * NGB;

  {
    const float4* tb = TBL + b * (NT * 4 * 64);
    for (int i = tid; i < NT * 4 * 64; i += 512) TBLl[i] = tb[i];
    const float* kgb = kg + b * (NT * 128);
    for (int i = tid; i < NT * 128; i += 512) kgl[i] = kgb[i];
  }
  __syncthreads();

  const int w = tid >> 6, lane = tid & 63;
  const int n = ng * 8 + w;
  const int item = b * NSN + n;

  // per-lane folded constants (L2-hot broadcasts)
  const float wa  = CONSTS[lane],       wbc = CONSTS[64 + lane];
  const float cg  = CONSTS[128 + lane], cp  = CONSTS[192 + lane];
  const float cc1 = CONSTS[256 + lane];
  const float w0 = Wnbr[lane], w1 = Wnbr[64 + lane];
  const float bgo0 = bgo[2 * lane], bgo1 = bgo[2 * lane + 1];
  const float wm2 = Wm2[lane], bm2s = bm2[0];
  const float c0 = c01[2 * n], c1 = c01[2 * n + 1];
  const int mself = mask[item];

  const float ql = qlocal[n * 64 + lane];
  qlS[w][lane] = ql;
  int jv = 0, mk = 0; float x0 = 0.f, x1 = 0.f;
  if (lane < 16) {
    jv = knn[n * 16 + lane];
    const float2 x01 = *(const float2*)(x_flat + (size_t)(b * NSN + jv) * 2);
    x0 = x01.x; x1 = x01.y;
    mk = mask[b * NSN + jv];
  }

  // ---- Pass 1: KNN logits (4 lanes per neighbor k) ----
  const int k = lane >> 2, d = lane & 3;
  const int jk = __shfl(jv, k);
  const float4* Sr = (const float4*)(S + jk * 64 + d * 16);
  const float4* qr = (const float4*)(&qlS[w][d * 16]);
  float acc = 0.f;
  #pragma unroll
  for (int i = 0; i < 4; ++i) {
    const float4 sv = Sr[i]; const float4 qv = qr[i];
    acc += sv.x * qv.x + sv.y * qv.y + sv.z * qv.z + sv.w * qv.w;
  }
  acc += __shfl_xor(acc, 1); acc += __shfl_xor(acc, 2);
  const float xk0 = __shfl(x0, k), xk1 = __shfl(x1, k);
  const int mkk = __shfl(mk, k);
  float logit = (acc + xk0 * c0 + xk1 * c1) * 0.125f;
  if (mkk != 0) logit = -10000.0f;
  float mx = logit;
  mx = fmaxf(mx, __shfl_xor(mx, 4));  mx = fmaxf(mx, __shfl_xor(mx, 8));
  mx = fmaxf(mx, __shfl_xor(mx, 16)); mx = fmaxf(mx, __shfl_xor(mx, 32));
  const float e = __expf(logit - mx);
  float s4 = e;
  s4 += __shfl_xor(s4, 4); s4 += __shfl_xor(s4, 8);
  s4 += __shfl_xor(s4, 16); s4 += __shfl_xor(s4, 32);
  const float attn = e / s4;
  float ax0 = attn * xk0, ax1 = attn * xk1;
  ax0 += __shfl_xor(ax0, 4); ax0 += __shfl_xor(ax0, 8);
  ax0 += __shfl_xor(ax0, 16); ax0 += __shfl_xor(ax0, 32);
  ax1 += __shfl_xor(ax1, 4); ax1 += __shfl_xor(ax1, 8);
  ax1 += __shfl_xor(ax1, 16); ax1 += __shfl_xor(ax1, 32);

  // ---- lf (lane=h) and L (lane=o) via 16 packed float2 row-gathers ----
  float lf = ax0 * w0 + ax1 * w1;
  float L  = ax0 * wa + ax1 * wbc;
  #pragma unroll 4
  for (int kk = 0; kk < 16; ++kk) {
    const int jr = __builtin_amdgcn_readlane(jv, kk);
    const float aw = rl_f(attn, 4 * kk);
    const float2 ss = SS[jr * 64 + lane];
    lf += aw * ss.x;
    L  += aw * ss.y;
  }

  // ---- global attention logits (head h = lane>>4, dims 2l,2l+1) ----
  const float2 q2 = *(const float2*)(qg + n * 128 + 2 * lane);
  float av[NT];
  #pragma unroll
  for (int t = 0; t < NT; ++t) {
    const float2 k2 = *(const float2*)&kgl[t * 128 + 2 * lane];
    float p = q2.x * k2.x + q2.y * k2.y;
    p += __shfl_xor(p, 1); p += __shfl_xor(p, 2);
    p += __shfl_xor(p, 4); p += __shfl_xor(p, 8);
    av[t] = p * 0.17677669529663687f;   // 1/sqrt(32)
  }
  float gm = av[0];
  #pragma unroll
  for (int t = 1; t < NT; ++t) gm = fmaxf(gm, av[t]);
  float gs = 0.f;
  #pragma unroll
  for (int t = 0; t < NT; ++t) { av[t] = __expf(av[t] - gm); gs += av[t]; }
  const float ginv = 1.0f / gs;
  #pragma unroll
  for (int t = 0; t < NT; ++t) av[t] *= ginv;

  // ---- g_out (lane -> 2l,2l+1) and M (lane -> o) from packed table ----
  float g0 = bgo0, g1 = bgo1, M = 0.f;
  #pragma unroll 2
  for (int t = 0; t < NT; ++t) {
    #pragma unroll
    for (int h = 0; h < 4; ++h) {
      const float a = rl_f(av[t], 16 * h);
      const float4 tb = TBLl[(t * 4 + h) * 64 + lane];
      g0 += a * tb.x; g1 += a * tb.y; M += a * tb.z;
    }
  }

  // ---- LayerNorm stats over 192 (lane covers lf[lane], g[2l], g[2l+1]) ----
  float s1 = lf + g0 + g1;
  float s2 = lf * lf + g0 * g0 + g1 * g1;
  #pragma unroll
  for (int o = 32; o; o >>= 1) { s1 += __shfl_xor(s1, o); s2 += __shfl_xor(s2, o); }
  const float mu  = s1 * (1.0f / 192.0f);
  const float var = s2 * (1.0f / 192.0f) - mu * mu;
  const float rinv = rsqrtf(var + 1e-5f);

  // ---- folded MLP: m1 -> GELU -> dot W_m2 ----
  const float m1 = rinv * (L + M + cc1 - mu * cg) + cp;
  const float gelu = 0.5f * m1 * (1.0f + erff(m1 * 0.7071067811865476f));
  float pr = gelu * wm2;
  #pragma unroll
  for (int o = 32; o; o >>= 1) pr += __shfl_xor(pr, o);
  float res = pr + bm2s;
  if (mself == 0) res = 0.f;
  if (lane == 0) out[item] = res;
}

extern "C" void kernel_launch(void* const* d_in, const int* in_sizes, int n_in,
                              void* d_out, int out_size, void* d_ws, size_t ws_size,
                              hipStream_t stream) {
  (void)in_sizes; (void)n_in; (void)out_size; (void)ws_size;
  const float* x_flat   = (const float*)d_in[0];
  const float* latent   = (const float*)d_in[1];
  const float* pos_emb  = (const float*)d_in[2];
  const float* face_emb = (const float*)d_in[3];
  const float* W_nbr = (const float*)d_in[4];
  const float* b_nbr = (const float*)d_in[5];
  const float* W_ql  = (const float*)d_in[6];
  const float* b_ql  = (const float*)d_in[7];
  const float* W_lat = (const float*)d_in[8];
  const float* b_lat = (const float*)d_in[9];
  const float* W_lf  = (const float*)d_in[10];
  const float* b_lf  = (const float*)d_in[11];
  const float* W_qg  = (const float*)d_in[12];
  const float* b_qg  = (const float*)d_in[13];
  const float* W_k   = (const float*)d_in[14];
  const float* b_k   = (const float*)d_in[15];
  const float* W_v   = (const float*)d_in[16];
  const float* b_v   = (const float*)d_in[17];
  const float* W_go  = (const float*)d_in[18];
  const float* b_go  = (const float*)d_in[19];
  const float* ln_g  = (const float*)d_in[20];
  const float* ln_b  = (const float*)d_in[21];
  const float* W_m1  = (const float*)d_in[22];
  const float* b_m1  = (const float*)d_in[23];
  const float* W_m2  = (const float*)d_in[24];
  const float* b_m2  = (const float*)d_in[25];
  const int* mask     = (const int*)d_in[26];
  const int* knn      = (const int*)d_in[27];
  const int* face_ids = (const int*)d_in[28];
  float* out = (float*)d_out;

  float* ws = (float*)d_ws;
  float* S      = ws;  ws += NSN * 64;
  float* qlocal = ws;  ws += NSN * 64;
  float* qgb    = ws;  ws += NSN * 128;
  float* c01    = ws;  ws += NSN * 2;
  float2* SSt   = (float2*)ws;  ws += NSN * 64 * 2;
  float* kgb    = ws;  ws += NB * NT * 128;
  float4* TBLt  = (float4*)ws;  ws += NB * NT * 4 * 64 * 4;
  float* CONSTS = ws;  ws += 5 * 64;

  precompute_sensor<<<149, 512, 0, stream>>>(pos_emb, face_emb, face_ids,
      W_nbr, b_nbr, W_ql, b_ql, W_qg, b_qg, W_m1, ln_g,
      S, qlocal, qgb, c01, SSt);
  precompute_latent<<<NB * NT + 1, 128, 0, stream>>>(latent, face_emb,
      W_lat, b_lat, W_lf, b_lf, W_k, b_k, W_v, b_v, W_go, W_m1, ln_g,
      ln_b, b_m1, W_nbr, b_go, kgb, TBLt, CONSTS);
  fused_main<<<NB * NGB, 512, 0, stream>>>(x_flat, mask, knn, W_nbr,
      S, qlocal, qgb, c01, kgb, SSt, TBLt, CONSTS,
      b_go, W_m2, b_m2, out);
}